// Round 7
// baseline (102.776 us; speedup 1.0000x reference)
//
#include <hip/hip_runtime.h>

typedef unsigned short u16;
typedef unsigned char u8;
typedef long long i64;
typedef __bf16 bf16x8 __attribute__((ext_vector_type(8)));
typedef float f32x4 __attribute__((ext_vector_type(4)));
typedef u16 u16x8 __attribute__((ext_vector_type(8)));

#define GLD16(g, l) __builtin_amdgcn_global_load_lds( \
    (const __attribute__((address_space(1))) void*)(g), \
    (__attribute__((address_space(3))) void*)(l), 16, 0, 0)

__device__ __forceinline__ float bf2f(u16 u) {
  return __uint_as_float(((unsigned)u) << 16);
}
__device__ __forceinline__ u16 f2bf(float f) {  // RNE
  unsigned u = __float_as_uint(f);
  return (u16)((u + 0x7fffu + ((u >> 16) & 1u)) >> 16);
}
// ---- software fp8 e4m3fn fallback codec ----
__device__ __forceinline__ u8 f8e_sw(float v) {
  unsigned u = __float_as_uint(v);
  unsigned s = (u >> 24) & 0x80u;
  u &= 0x7fffffffu;
  if (u < 0x3c000000u) return (u8)s;
  int b = (int)((u + 0x7FFFFu + ((u >> 20) & 1u)) >> 20) - 960;
  b = b < 8 ? 8 : (b > 126 ? 126 : b);
  return (u8)(b | s);
}
__device__ __forceinline__ float f8d_sw(u8 b) {
  if (!(b & 0x7f)) return 0.0f;
  float v = __uint_as_float((((unsigned)(b & 0x7fu)) << 20) + 0x3C000000u);
  return (b & 0x80u) ? -v : v;
}
// ---- hardware fp8 codec (gfx950) with sw fallback ----
__device__ __forceinline__ unsigned pk4(float a, float b, float c, float d) {
#if __has_builtin(__builtin_amdgcn_cvt_pk_fp8_f32)
  int r = __builtin_amdgcn_cvt_pk_fp8_f32(a, b, 0, false);
  r = __builtin_amdgcn_cvt_pk_fp8_f32(c, d, r, true);
  return (unsigned)r;
#else
  return (unsigned)f8e_sw(a) | ((unsigned)f8e_sw(b) << 8) |
         ((unsigned)f8e_sw(c) << 16) | ((unsigned)f8e_sw(d) << 24);
#endif
}
__device__ __forceinline__ float f8df(u8 b) {
#if __has_builtin(__builtin_amdgcn_cvt_f32_fp8)
  return __builtin_amdgcn_cvt_f32_fp8((int)b, 0);
#else
  return f8d_sw(b);
#endif
}
// 16B-slot swizzle key (bank-conflict-free fragment reads from GLD16-linear LDS)
__device__ __forceinline__ int sig(int r) { return (r ^ (r >> 3)) & 7; }

// ---- weight prep: wtT[d][c] = ((Wq+Wk+Wv)/3)[c][d], woutT[d][c] = w_out[c][d]
__global__ void combine_w(const float* __restrict__ wqkv, const float* __restrict__ wout,
                          u16* __restrict__ wtT, u16* __restrict__ woutT) {
  int c = blockIdx.x, d = threadIdx.x;
  float t = (wqkv[c * 768 + d] + wqkv[c * 768 + 256 + d] + wqkv[c * 768 + 512 + d]) * (1.0f / 3.0f);
  wtT[d * 256 + c] = f2bf(t);
  woutT[d * 256 + c] = f2bf(wout[c * 256 + d]);
}

// ---- fused GroupNorm + GEMM-T, double-buffered. Tile 64x256, 8 waves.
// Epilogue: Kt8 (LDS repack -> 16B stores) and Q8 (LDS repack -> 16B stores).
__global__ __launch_bounds__(512) void gnT(
    const float* __restrict__ x, const float* __restrict__ gamma,
    const float* __restrict__ beta, const u16* __restrict__ wtT,
    u8* __restrict__ Q8, u8* __restrict__ Kt8) {
  __shared__ u16 lA[2][64 * 64];
  __shared__ u16 lB[2][256 * 64];
  const int m0 = blockIdx.x * 64;   // global pixel base (single batch per block)
  const int z = m0 >> 10;
  const int t = threadIdx.x, lane = t & 63;
  const int w = t >> 6, wr = w >> 2, wc = w & 3;
  f32x4 acc[2][4] = {};

#define GNT_STAGE(B, K0)                                                        \
  {                                                                             \
    _Pragma("unroll") for (int ch = 0; ch < 4; ch++) {                          \
      int flat = ch * 512 + t, row = flat >> 3, slot = flat & 7;                \
      GLD16(wtT + (size_t)row * 256 + (K0) + (slot ^ sig(row)) * 8,             \
            lB[B] + flat * 8);                                                  \
    }                                                                           \
    int row = t >> 3, grp = t & 7;                                              \
    const float* xp = x + (size_t)(m0 + row) * 256 + (K0) + grp * 8;            \
    float4 a = *(const float4*)xp, b = *(const float4*)(xp + 4);                \
    float mu = (a.x + a.y + a.z + a.w + b.x + b.y + b.z + b.w) * 0.125f;        \
    float d0 = a.x - mu, d1 = a.y - mu, d2 = a.z - mu, d3 = a.w - mu;           \
    float d4 = b.x - mu, d5 = b.y - mu, d6 = b.z - mu, d7 = b.w - mu;           \
    float var = (d0 * d0 + d1 * d1 + d2 * d2 + d3 * d3 +                        \
                 d4 * d4 + d5 * d5 + d6 * d6 + d7 * d7) * 0.125f;               \
    float rs = rsqrtf(var + 1e-6f);                                             \
    const float4 g0 = *(const float4*)(gamma + (K0) + grp * 8);                 \
    const float4 g1 = *(const float4*)(gamma + (K0) + grp * 8 + 4);             \
    const float4 e0 = *(const float4*)(beta + (K0) + grp * 8);                  \
    const float4 e1 = *(const float4*)(beta + (K0) + grp * 8 + 4);              \
    u16x8 o;                                                                    \
    o[0] = f2bf(g0.x * (d0 * rs) + e0.x); o[1] = f2bf(g0.y * (d1 * rs) + e0.y); \
    o[2] = f2bf(g0.z * (d2 * rs) + e0.z); o[3] = f2bf(g0.w * (d3 * rs) + e0.w); \
    o[4] = f2bf(g1.x * (d4 * rs) + e1.x); o[5] = f2bf(g1.y * (d5 * rs) + e1.y); \
    o[6] = f2bf(g1.z * (d6 * rs) + e1.z); o[7] = f2bf(g1.w * (d7 * rs) + e1.w); \
    *(u16x8*)(lA[B] + row * 64 + (grp ^ sig(row)) * 8) = o;                     \
  }

  GNT_STAGE(0, 0);
  __syncthreads();
  for (int it = 0; it < 4; it++) {
    if (it < 3) { GNT_STAGE((it + 1) & 1, (it + 1) * 64); }
    const u16* la = lA[it & 1];
    const u16* lb = lB[it & 1];
#pragma unroll
    for (int kk = 0; kk < 2; kk++) {
      bf16x8 af[2], bfr[4];
#pragma unroll
      for (int mi = 0; mi < 2; mi++) {
        int m = wr * 32 + mi * 16 + (lane & 15);
        af[mi] = *(const bf16x8*)(la + m * 64 + ((kk * 32 + (lane >> 4) * 8) ^ (sig(m) << 3)));
      }
#pragma unroll
      for (int ni = 0; ni < 4; ni++) {
        int n = wc * 64 + ni * 16 + (lane & 15);
        bfr[ni] = *(const bf16x8*)(lb + n * 64 + ((kk * 32 + (lane >> 4) * 8) ^ (sig(n) << 3)));
      }
#pragma unroll
      for (int mi = 0; mi < 2; mi++)
#pragma unroll
        for (int ni = 0; ni < 4; ni++)
          acc[mi][ni] = __builtin_amdgcn_mfma_f32_16x16x32_bf16(af[mi], bfr[ni], acc[mi][ni], 0, 0, 0);
    }
    __syncthreads();
  }

  const int rb = m0 + wr * 32 + ((lane >> 4) << 2);  // global pixel, %4 == 0
  const int cb = wc * 64 + (lane & 15);
  u8* kt = (u8*)lB[0];          // 16KB: Kt8 repack [1024 rows][16B]
  u8* qtile = (u8*)lB[1];       // 20KB: Q8 repack [256 c][80B stride, 64B data]
#pragma unroll
  for (int mi = 0; mi < 2; mi++)
#pragma unroll
    for (int ni = 0; ni < 4; ni++) {
      int P0 = rb + mi * 16, c = cb + ni * 16;
      int pl = P0 - m0;                     // 0..63, %4==0
      unsigned pk = pk4(acc[mi][ni][0], acc[mi][ni][1], acc[mi][ni][2], acc[mi][ni][3]);
#pragma unroll
      for (int j = 0; j < 4; j++)
        kt[(j * 256 + c) * 16 + (pl >> 2)] = (u8)(pk >> (8 * j));
      *(unsigned*)(qtile + c * 80 + pl) = pk;
    }
  __syncthreads();
  const int ckb = (m0 & 1023) >> 2;
  u8* Kz = Kt8 + (size_t)z * 262144;
  u8* Qz = Q8 + (size_t)z * 262144;
#pragma unroll
  for (int r2 = 0; r2 < 2; r2++) {
    int r = t * 2 + r2;
    uint4 v = *(const uint4*)(kt + r * 16);
    *(uint4*)(Kz + (size_t)r * 256 + ckb) = v;
  }
#pragma unroll
  for (int ph = 0; ph < 2; ph++) {
    int idx = ph * 512 + t, c = idx >> 2, q = idx & 3;
    uint4 v = *(const uint4*)(qtile + c * 80 + q * 16);
    *(uint4*)(Qz + (size_t)c * 1024 + (m0 & 1023) + q * 16) = v;
  }
#undef GNT_STAGE
}

// ---- GEMM-S (fp8): Et[p,i] = fp8(exp((Q@K)[i,p]/16)) + row partial sums.
// Single-stage BK=256 (full K), tile 128x128, 4 waves.
__global__ __launch_bounds__(256) void gemm_s8(
    const u8* __restrict__ Q8, const u8* __restrict__ Kt8,
    u8* __restrict__ Et, float* __restrict__ partials) {
  __shared__ u8 lA[128 * 256];
  __shared__ u8 lB[128 * 256];
  const int z = blockIdx.z;
  const u8* Az = Q8 + (size_t)z * 262144;
  const u8* Bz = Kt8 + (size_t)z * 262144;
  u8* Ez = Et + (size_t)z * 1048576;
  const int m0 = blockIdx.x * 128, n0 = blockIdx.y * 128;
  const int t = threadIdx.x, lane = t & 63;
  const int wr = (t >> 6) >> 1, wc = (t >> 6) & 1;
  f32x4 acc[4][4] = {};

#pragma unroll
  for (int ch = 0; ch < 8; ch++) {
    int flat = ch * 256 + t, row = flat >> 4, slot = flat & 15;
    GLD16(Az + (size_t)(m0 + row) * 256 + (slot ^ sig(row)) * 16, lA + flat * 16);
  }
#pragma unroll
  for (int ch = 0; ch < 8; ch++) {
    int flat = ch * 256 + t, row = flat >> 4, slot = flat & 15;
    GLD16(Bz + (size_t)(n0 + row) * 256 + (slot ^ sig(row)) * 16, lB + flat * 16);
  }
  __syncthreads();
#pragma unroll
  for (int kk = 0; kk < 8; kk++) {
    i64 af[4], bfv[4];
    int koff = kk * 32 + (lane >> 4) * 8;
#pragma unroll
    for (int mi = 0; mi < 4; mi++) {
      int m = wr * 64 + mi * 16 + (lane & 15);
      af[mi] = *(const i64*)(lA + m * 256 + (koff ^ (sig(m) << 4)));
    }
#pragma unroll
    for (int ni = 0; ni < 4; ni++) {
      int n = wc * 64 + ni * 16 + (lane & 15);
      bfv[ni] = *(const i64*)(lB + n * 256 + (koff ^ (sig(n) << 4)));
    }
#pragma unroll
    for (int mi = 0; mi < 4; mi++)
#pragma unroll
      for (int ni = 0; ni < 4; ni++)
        acc[mi][ni] = __builtin_amdgcn_mfma_f32_16x16x32_fp8_fp8(af[mi], bfv[ni], acc[mi][ni], 0, 0, 0);
  }
  __syncthreads();
  u8* ldsC = lA;  // 128p x 128i fp8 tile
  const int rbl = wr * 64 + ((lane >> 4) << 2);  // local i
  const int cbl = wc * 64 + (lane & 15);         // local p
  const float SCL = 0.0625f * 1.44269504089f;    // exp(x) = exp2(x*log2e)
  float ps[4][4] = {};
#pragma unroll
  for (int mi = 0; mi < 4; mi++)
#pragma unroll
    for (int ni = 0; ni < 4; ni++) {
      int pl = cbl + ni * 16, ib = rbl + mi * 16;
      float e0 = exp2f(acc[mi][ni][0] * SCL);
      float e1 = exp2f(acc[mi][ni][1] * SCL);
      float e2 = exp2f(acc[mi][ni][2] * SCL);
      float e3 = exp2f(acc[mi][ni][3] * SCL);
      ps[mi][0] += e0; ps[mi][1] += e1; ps[mi][2] += e2; ps[mi][3] += e3;
      *(unsigned*)(ldsC + pl * 128 + (ib ^ ((pl & 7) << 4))) = pk4(e0, e1, e2, e3);
    }
#pragma unroll
  for (int mi = 0; mi < 4; mi++)
#pragma unroll
    for (int j = 0; j < 4; j++) {
      float v = ps[mi][j];
      v += __shfl_xor(v, 1); v += __shfl_xor(v, 2);
      v += __shfl_xor(v, 4); v += __shfl_xor(v, 8);
      if ((lane & 15) == 0)
        partials[(size_t)(z * 1024 + m0 + rbl + mi * 16 + j) * 16 + blockIdx.y * 2 + wc] = v;
    }
  __syncthreads();
#pragma unroll
  for (int ph = 0; ph < 4; ph++) {
    int pl = ph * 32 + (t >> 3), ich = (t & 7) * 16;
    uint4 v = *(const uint4*)(ldsC + pl * 128 + (ich ^ ((pl & 7) << 4)));
    *(uint4*)(Ez + (size_t)(n0 + pl) * 1024 + m0 + ich) = v;
  }
}

// ---- Qt8[c][i] = fp8(Q[i][c] * (1024/L[i])): transpose + rinv fold, with
// the partials reduction (rinv) fused in.
__global__ __launch_bounds__(256) void qt8(
    const u8* __restrict__ Q8, const float* __restrict__ partials, u8* __restrict__ Qt) {
  __shared__ u8 tile[64][260];
  __shared__ float rv[64];
  const int z = blockIdx.y, i0 = blockIdx.x * 64;
  const u8* src = Q8 + (size_t)z * 262144;
  u8* dst = Qt + (size_t)z * 262144;
  const int t = threadIdx.x;
#pragma unroll
  for (int q = 0; q < 4; q++) {
    uint4 v = *(const uint4*)(src + (size_t)(i0 + (t >> 2)) * 256 + (t & 3) * 64 + q * 16);
    *(uint4*)(&tile[t >> 2][(t & 3) * 64 + q * 16]) = v;
  }
  if (t < 64) {
    const float4* p = (const float4*)(partials + (size_t)(z * 1024 + i0 + t) * 16);
    float4 a = p[0], b = p[1], c = p[2], d = p[3];
    float s = ((a.x + a.y) + (a.z + a.w)) + ((b.x + b.y) + (b.z + b.w)) +
              ((c.x + c.y) + (c.z + c.w)) + ((d.x + d.y) + (d.z + d.w));
    rv[t] = 1024.0f / s;
  }
  __syncthreads();
#pragma unroll
  for (int q = 0; q < 4; q++) {
    unsigned wd[4];
#pragma unroll
    for (int d = 0; d < 4; d++) {
      float f[4];
#pragma unroll
      for (int e = 0; e < 4; e++) {
        int i = q * 16 + d * 4 + e;
        f[e] = f8df(tile[i][t]) * rv[i];
      }
      wd[d] = pk4(f[0], f[1], f[2], f[3]);
    }
    uint4 v = {wd[0], wd[1], wd[2], wd[3]};
    *(uint4*)(dst + (size_t)t * 1024 + i0 + q * 16) = v;
  }
}

// ---- FUSED GEMM-O + GEMM-F:
// phase 1: ob[p,c] = (1/1024)*sum_i Et[p,i]*Qt[c,i]  (fp8 MFMA, dbuf GLD16)
//          -> bf16 [128][256] XOR-swizzled LDS tile
// phase 2: final[p,d] = sum_c ob[p,c]*woutT[d,c] + x[p,d]  (bf16 MFMA, dbuf)
// LDS alias map (128KB): [0,32K)=p1 A dbuf, [32K,96K)=p1 B dbuf;
//                        [0,64K)=ob tile,   [64K,128K)=wout dbuf.
__global__ __launch_bounds__(512) void gemm_of(
    const u8* __restrict__ Et, const u8* __restrict__ Qt,
    const u16* __restrict__ woutT, const float* __restrict__ x,
    float* __restrict__ C) {
  __shared__ char smem[131072];
  const int z = blockIdx.y;
  const u8* Az = Et + (size_t)z * 1048576;
  const u8* Bz = Qt + (size_t)z * 262144;
  const int m0 = blockIdx.x * 128;
  const int t = threadIdx.x, lane = t & 63;
  const int w = t >> 6, wr = w >> 2, wc = w & 3;
  f32x4 acc[4][4] = {};

#define O8_STAGE(B, K0)                                                       \
  {                                                                           \
    u8* la_ = (u8*)smem + (B) * 16384;                                        \
    u8* lb_ = (u8*)smem + 32768 + (B) * 32768;                                \
    _Pragma("unroll") for (int ch = 0; ch < 2; ch++) {                        \
      int flat = ch * 512 + t, row = flat >> 3, slot = flat & 7;              \
      GLD16(Az + (size_t)(m0 + row) * 1024 + (K0) + (slot ^ sig(row)) * 16,   \
            la_ + flat * 16);                                                 \
    }                                                                         \
    _Pragma("unroll") for (int ch = 0; ch < 4; ch++) {                        \
      int flat = ch * 512 + t, row = flat >> 3, slot = flat & 7;              \
      GLD16(Bz + (size_t)row * 1024 + (K0) + (slot ^ sig(row)) * 16,          \
            lb_ + flat * 16);                                                 \
    }                                                                         \
  }

  O8_STAGE(0, 0);
  __syncthreads();
  for (int it = 0; it < 8; it++) {
    if (it < 7) { O8_STAGE((it + 1) & 1, (it + 1) * 128); }
    const u8* la = (const u8*)smem + (it & 1) * 16384;
    const u8* lb = (const u8*)smem + 32768 + (it & 1) * 32768;
#pragma unroll
    for (int kk = 0; kk < 4; kk++) {
      i64 af[4], bfv[4];
      int koff = kk * 32 + (lane >> 4) * 8;
#pragma unroll
      for (int mi = 0; mi < 4; mi++) {
        int m = wr * 64 + mi * 16 + (lane & 15);
        af[mi] = *(const i64*)(la + m * 128 + (koff ^ (sig(m) << 4)));
      }
#pragma unroll
      for (int ni = 0; ni < 4; ni++) {
        int n = wc * 64 + ni * 16 + (lane & 15);
        bfv[ni] = *(const i64*)(lb + n * 128 + (koff ^ (sig(n) << 4)));
      }
#pragma unroll
      for (int mi = 0; mi < 4; mi++)
#pragma unroll
        for (int ni = 0; ni < 4; ni++)
          acc[mi][ni] = __builtin_amdgcn_mfma_f32_16x16x32_fp8_fp8(af[mi], bfv[ni], acc[mi][ni], 0, 0, 0);
    }
    __syncthreads();
  }
#undef O8_STAGE

  // phase 1 -> 2 transition: stage wout k0=0 (overlaps dead p1B[1]) and spill
  // acc to the bf16 ob tile at [0,64K) (overlaps dead p1A/p1B[0]).
#define W_STAGE(B, K0)                                                        \
  {                                                                           \
    u16* wb_ = (u16*)(smem + 65536 + (B) * 32768);                            \
    _Pragma("unroll") for (int ch = 0; ch < 4; ch++) {                        \
      int flat = ch * 512 + t, row = flat >> 3, slot = flat & 7;              \
      GLD16(woutT + (size_t)row * 256 + (K0) + (slot ^ sig(row)) * 8,         \
            (u8*)wb_ + flat * 16);                                            \
    }                                                                         \
  }
  W_STAGE(0, 0);
  {
    const int rbl = wr * 64 + ((lane >> 4) << 2);
    const int cbl = wc * 64 + (lane & 15);
#pragma unroll
    for (int mi = 0; mi < 4; mi++)
#pragma unroll
      for (int ni = 0; ni < 4; ni++)
#pragma unroll
        for (int j = 0; j < 4; j++) {
          int pl = rbl + mi * 16 + j, c = cbl + ni * 16;
          int byteoff = (pl * 512 + c * 2) ^ ((pl & 7) << 4);
          *(u16*)(smem + byteoff) = f2bf(acc[mi][ni][j] * (1.0f / 1024.0f));
        }
  }
  __syncthreads();

  f32x4 acc2[4][4] = {};
  for (int it2 = 0; it2 < 4; it2++) {
    if (it2 < 3) { W_STAGE((it2 + 1) & 1, (it2 + 1) * 64); }
    const u16* lb = (const u16*)(smem + 65536 + (it2 & 1) * 32768);
#pragma unroll
    for (int kk = 0; kk < 2; kk++) {
      bf16x8 af[4], bfr[4];
#pragma unroll
      for (int mi = 0; mi < 4; mi++) {
        int m = wr * 64 + mi * 16 + (lane & 15);
        int kg = it2 * 64 + kk * 32 + (lane >> 4) * 8;
        af[mi] = *(const bf16x8*)(smem + ((m * 512 + kg * 2) ^ ((m & 7) << 4)));
      }
#pragma unroll
      for (int ni = 0; ni < 4; ni++) {
        int n = wc * 64 + ni * 16 + (lane & 15);
        bfr[ni] = *(const bf16x8*)(lb + n * 64 + ((kk * 32 + (lane >> 4) * 8) ^ (sig(n) << 3)));
      }
#pragma unroll
      for (int mi = 0; mi < 4; mi++)
#pragma unroll
        for (int ni = 0; ni < 4; ni++)
          acc2[mi][ni] = __builtin_amdgcn_mfma_f32_16x16x32_bf16(af[mi], bfr[ni], acc2[mi][ni], 0, 0, 0);
    }
    __syncthreads();
  }
#undef W_STAGE

  const int Pb = z * 1024 + m0 + wr * 64 + ((lane >> 4) << 2);
  const int cb = wc * 64 + (lane & 15);
#pragma unroll
  for (int mi = 0; mi < 4; mi++)
#pragma unroll
    for (int ni = 0; ni < 4; ni++)
#pragma unroll
      for (int j = 0; j < 4; j++) {
        size_t idx = (size_t)(Pb + mi * 16 + j) * 256 + cb + ni * 16;
        C[idx] = acc2[mi][ni][j] + x[idx];
      }
}

extern "C" void kernel_launch(void* const* d_in, const int* in_sizes, int n_in,
                              void* d_out, int out_size, void* d_ws, size_t ws_size,
                              hipStream_t stream) {
  (void)in_sizes; (void)n_in; (void)out_size; (void)ws_size;
  const float* x = (const float*)d_in[0];
  const float* gamma = (const float*)d_in[1];
  const float* beta = (const float*)d_in[2];
  const float* wqkv = (const float*)d_in[3];
  const float* wout = (const float*)d_in[4];
  float* outp = (float*)d_out;

  char* ws = (char*)d_ws;
  const size_t MB = 1024 * 1024;
  u16* wtT = (u16*)(ws + 0);                     // 128K
  u16* woutT = (u16*)(ws + (128 << 10));         // 128K
  float* partials = (float*)(ws + (512 << 10));  // 2M
  u8* Q8 = (u8*)(ws + 3 * MB);                   // 8M  fp8 Tt layout (Q rows flat)
  u8* Kt8 = (u8*)(ws + 12 * MB);                 // 8M  fp8 [z][1024][256]
  u8* Qt = (u8*)(ws + 21 * MB);                  // 8M  fp8 [z][256][1024]
  u8* Et = (u8*)(ws + 30 * MB);                  // 32M fp8 [z][p][i]

  combine_w<<<256, 256, 0, stream>>>(wqkv, wout, wtT, woutT);
  gnT<<<512, 512, 0, stream>>>(x, gamma, beta, wtT, Q8, Kt8);
  gemm_s8<<<dim3(8, 8, 32), 256, 0, stream>>>(Q8, Kt8, Et, partials);
  qt8<<<dim3(16, 32), 256, 0, stream>>>(Q8, partials, Qt);
  gemm_of<<<dim3(8, 32), 512, 0, stream>>>(Et, Qt, woutT, x, outp);
}

// Round 8
// 91.359 us; speedup vs baseline: 1.1250x; 1.1250x over previous
//
#include <hip/hip_runtime.h>

typedef unsigned short u16;
typedef unsigned char u8;
typedef long long i64;
typedef __bf16 bf16x8 __attribute__((ext_vector_type(8)));
typedef float f32x4 __attribute__((ext_vector_type(4)));
typedef u16 u16x8 __attribute__((ext_vector_type(8)));

#define GLD16(g, l) __builtin_amdgcn_global_load_lds( \
    (const __attribute__((address_space(1))) void*)(g), \
    (__attribute__((address_space(3))) void*)(l), 16, 0, 0)
// counted vmcnt wait (N literal) -- lets prefetch loads stay in flight across barriers
#define VMW(N) asm volatile("s_waitcnt vmcnt(" #N ")" ::: "memory")

__device__ __forceinline__ float bf2f(u16 u) {
  return __uint_as_float(((unsigned)u) << 16);
}
__device__ __forceinline__ u16 f2bf(float f) {  // RNE
  unsigned u = __float_as_uint(f);
  return (u16)((u + 0x7fffu + ((u >> 16) & 1u)) >> 16);
}
// ---- software fp8 e4m3fn fallback codec ----
__device__ __forceinline__ u8 f8e_sw(float v) {
  unsigned u = __float_as_uint(v);
  unsigned s = (u >> 24) & 0x80u;
  u &= 0x7fffffffu;
  if (u < 0x3c000000u) return (u8)s;
  int b = (int)((u + 0x7FFFFu + ((u >> 20) & 1u)) >> 20) - 960;
  b = b < 8 ? 8 : (b > 126 ? 126 : b);
  return (u8)(b | s);
}
__device__ __forceinline__ float f8d_sw(u8 b) {
  if (!(b & 0x7f)) return 0.0f;
  float v = __uint_as_float((((unsigned)(b & 0x7fu)) << 20) + 0x3C000000u);
  return (b & 0x80u) ? -v : v;
}
// ---- hardware fp8 codec (gfx950) with sw fallback ----
__device__ __forceinline__ unsigned pk4(float a, float b, float c, float d) {
#if __has_builtin(__builtin_amdgcn_cvt_pk_fp8_f32)
  int r = __builtin_amdgcn_cvt_pk_fp8_f32(a, b, 0, false);
  r = __builtin_amdgcn_cvt_pk_fp8_f32(c, d, r, true);
  return (unsigned)r;
#else
  return (unsigned)f8e_sw(a) | ((unsigned)f8e_sw(b) << 8) |
         ((unsigned)f8e_sw(c) << 16) | ((unsigned)f8e_sw(d) << 24);
#endif
}
__device__ __forceinline__ float f8df(u8 b) {
#if __has_builtin(__builtin_amdgcn_cvt_f32_fp8)
  return __builtin_amdgcn_cvt_f32_fp8((int)b, 0);
#else
  return f8d_sw(b);
#endif
}
// 16B-slot swizzle key (bank-conflict-free fragment reads from GLD16-linear LDS)
__device__ __forceinline__ int sig(int r) { return (r ^ (r >> 3)) & 7; }

// ---- weight prep: wtT[d][c] = ((Wq+Wk+Wv)/3)[c][d], woutT[d][c] = w_out[c][d]
__global__ void combine_w(const float* __restrict__ wqkv, const float* __restrict__ wout,
                          u16* __restrict__ wtT, u16* __restrict__ woutT) {
  int c = blockIdx.x, d = threadIdx.x;
  float t = (wqkv[c * 768 + d] + wqkv[c * 768 + 256 + d] + wqkv[c * 768 + 512 + d]) * (1.0f / 3.0f);
  wtT[d * 256 + c] = f2bf(t);
  woutT[d * 256 + c] = f2bf(wout[c * 256 + d]);
}

// ---- fused GroupNorm + GEMM-T, double-buffered. Tile 64x256, 8 waves.
// Epilogue: Kt8 (LDS repack -> 16B stores) and Q8 (LDS repack -> 16B stores).
__global__ __launch_bounds__(512) void gnT(
    const float* __restrict__ x, const float* __restrict__ gamma,
    const float* __restrict__ beta, const u16* __restrict__ wtT,
    u8* __restrict__ Q8, u8* __restrict__ Kt8) {
  __shared__ u16 lA[2][64 * 64];
  __shared__ u16 lB[2][256 * 64];
  const int m0 = blockIdx.x * 64;   // global pixel base (single batch per block)
  const int z = m0 >> 10;
  const int t = threadIdx.x, lane = t & 63;
  const int w = t >> 6, wr = w >> 2, wc = w & 3;
  f32x4 acc[2][4] = {};

#define GNT_STAGE(B, K0)                                                        \
  {                                                                             \
    _Pragma("unroll") for (int ch = 0; ch < 4; ch++) {                          \
      int flat = ch * 512 + t, row = flat >> 3, slot = flat & 7;                \
      GLD16(wtT + (size_t)row * 256 + (K0) + (slot ^ sig(row)) * 8,             \
            lB[B] + flat * 8);                                                  \
    }                                                                           \
    int row = t >> 3, grp = t & 7;                                              \
    const float* xp = x + (size_t)(m0 + row) * 256 + (K0) + grp * 8;            \
    float4 a = *(const float4*)xp, b = *(const float4*)(xp + 4);                \
    float mu = (a.x + a.y + a.z + a.w + b.x + b.y + b.z + b.w) * 0.125f;        \
    float d0 = a.x - mu, d1 = a.y - mu, d2 = a.z - mu, d3 = a.w - mu;           \
    float d4 = b.x - mu, d5 = b.y - mu, d6 = b.z - mu, d7 = b.w - mu;           \
    float var = (d0 * d0 + d1 * d1 + d2 * d2 + d3 * d3 +                        \
                 d4 * d4 + d5 * d5 + d6 * d6 + d7 * d7) * 0.125f;               \
    float rs = rsqrtf(var + 1e-6f);                                             \
    const float4 g0 = *(const float4*)(gamma + (K0) + grp * 8);                 \
    const float4 g1 = *(const float4*)(gamma + (K0) + grp * 8 + 4);             \
    const float4 e0 = *(const float4*)(beta + (K0) + grp * 8);                  \
    const float4 e1 = *(const float4*)(beta + (K0) + grp * 8 + 4);              \
    u16x8 o;                                                                    \
    o[0] = f2bf(g0.x * (d0 * rs) + e0.x); o[1] = f2bf(g0.y * (d1 * rs) + e0.y); \
    o[2] = f2bf(g0.z * (d2 * rs) + e0.z); o[3] = f2bf(g0.w * (d3 * rs) + e0.w); \
    o[4] = f2bf(g1.x * (d4 * rs) + e1.x); o[5] = f2bf(g1.y * (d5 * rs) + e1.y); \
    o[6] = f2bf(g1.z * (d6 * rs) + e1.z); o[7] = f2bf(g1.w * (d7 * rs) + e1.w); \
    *(u16x8*)(lA[B] + row * 64 + (grp ^ sig(row)) * 8) = o;                     \
  }

  GNT_STAGE(0, 0);
  __syncthreads();
  for (int it = 0; it < 4; it++) {
    if (it < 3) { GNT_STAGE((it + 1) & 1, (it + 1) * 64); }
    const u16* la = lA[it & 1];
    const u16* lb = lB[it & 1];
#pragma unroll
    for (int kk = 0; kk < 2; kk++) {
      bf16x8 af[2], bfr[4];
#pragma unroll
      for (int mi = 0; mi < 2; mi++) {
        int m = wr * 32 + mi * 16 + (lane & 15);
        af[mi] = *(const bf16x8*)(la + m * 64 + ((kk * 32 + (lane >> 4) * 8) ^ (sig(m) << 3)));
      }
#pragma unroll
      for (int ni = 0; ni < 4; ni++) {
        int n = wc * 64 + ni * 16 + (lane & 15);
        bfr[ni] = *(const bf16x8*)(lb + n * 64 + ((kk * 32 + (lane >> 4) * 8) ^ (sig(n) << 3)));
      }
#pragma unroll
      for (int mi = 0; mi < 2; mi++)
#pragma unroll
        for (int ni = 0; ni < 4; ni++)
          acc[mi][ni] = __builtin_amdgcn_mfma_f32_16x16x32_bf16(af[mi], bfr[ni], acc[mi][ni], 0, 0, 0);
    }
    __syncthreads();
  }

  const int rb = m0 + wr * 32 + ((lane >> 4) << 2);  // global pixel, %4 == 0
  const int cb = wc * 64 + (lane & 15);
  u8* kt = (u8*)lB[0];          // 16KB: Kt8 repack [1024 rows][16B]
  u8* qtile = (u8*)lB[1];       // 20KB: Q8 repack [256 c][80B stride, 64B data]
#pragma unroll
  for (int mi = 0; mi < 2; mi++)
#pragma unroll
    for (int ni = 0; ni < 4; ni++) {
      int P0 = rb + mi * 16, c = cb + ni * 16;
      int pl = P0 - m0;                     // 0..63, %4==0
      unsigned pk = pk4(acc[mi][ni][0], acc[mi][ni][1], acc[mi][ni][2], acc[mi][ni][3]);
#pragma unroll
      for (int j = 0; j < 4; j++)
        kt[(j * 256 + c) * 16 + (pl >> 2)] = (u8)(pk >> (8 * j));
      *(unsigned*)(qtile + c * 80 + pl) = pk;
    }
  __syncthreads();
  const int ckb = (m0 & 1023) >> 2;
  u8* Kz = Kt8 + (size_t)z * 262144;
  u8* Qz = Q8 + (size_t)z * 262144;
#pragma unroll
  for (int r2 = 0; r2 < 2; r2++) {
    int r = t * 2 + r2;
    uint4 v = *(const uint4*)(kt + r * 16);
    *(uint4*)(Kz + (size_t)r * 256 + ckb) = v;
  }
#pragma unroll
  for (int ph = 0; ph < 2; ph++) {
    int idx = ph * 512 + t, c = idx >> 2, q = idx & 3;
    uint4 v = *(const uint4*)(qtile + c * 80 + q * 16);
    *(uint4*)(Qz + (size_t)c * 1024 + (m0 & 1023) + q * 16) = v;
  }
#undef GNT_STAGE
}

// ---- GEMM-S (fp8): Et[p,i] = fp8(exp((Q@K)[i,p]/16)) + row partial sums.
// Single-stage BK=256 (full K), tile 128x128, 4 waves.
// Grid (z=32, mp=64): id%8 = z%8 -> all blocks of one z on one XCD (L2 reuse).
__global__ __launch_bounds__(256) void gemm_s8(
    const u8* __restrict__ Q8, const u8* __restrict__ Kt8,
    u8* __restrict__ Et, float* __restrict__ partials) {
  __shared__ u8 lA[128 * 256];
  __shared__ u8 lB[128 * 256];
  const int z = blockIdx.x;
  const int mb = blockIdx.y & 7, pb = blockIdx.y >> 3;
  const u8* Az = Q8 + (size_t)z * 262144;
  const u8* Bz = Kt8 + (size_t)z * 262144;
  u8* Ez = Et + (size_t)z * 1048576;
  const int m0 = mb * 128, n0 = pb * 128;
  const int t = threadIdx.x, lane = t & 63;
  const int wr = (t >> 6) >> 1, wc = (t >> 6) & 1;
  f32x4 acc[4][4] = {};

#pragma unroll
  for (int ch = 0; ch < 8; ch++) {
    int flat = ch * 256 + t, row = flat >> 4, slot = flat & 15;
    GLD16(Az + (size_t)(m0 + row) * 256 + (slot ^ sig(row)) * 16, lA + flat * 16);
  }
#pragma unroll
  for (int ch = 0; ch < 8; ch++) {
    int flat = ch * 256 + t, row = flat >> 4, slot = flat & 15;
    GLD16(Bz + (size_t)(n0 + row) * 256 + (slot ^ sig(row)) * 16, lB + flat * 16);
  }
  __syncthreads();
#pragma unroll
  for (int kk = 0; kk < 8; kk++) {
    i64 af[4], bfv[4];
    int koff = kk * 32 + (lane >> 4) * 8;
#pragma unroll
    for (int mi = 0; mi < 4; mi++) {
      int m = wr * 64 + mi * 16 + (lane & 15);
      af[mi] = *(const i64*)(lA + m * 256 + (koff ^ (sig(m) << 4)));
    }
#pragma unroll
    for (int ni = 0; ni < 4; ni++) {
      int n = wc * 64 + ni * 16 + (lane & 15);
      bfv[ni] = *(const i64*)(lB + n * 256 + (koff ^ (sig(n) << 4)));
    }
#pragma unroll
    for (int mi = 0; mi < 4; mi++)
#pragma unroll
      for (int ni = 0; ni < 4; ni++)
        acc[mi][ni] = __builtin_amdgcn_mfma_f32_16x16x32_fp8_fp8(af[mi], bfv[ni], acc[mi][ni], 0, 0, 0);
  }
  __syncthreads();
  u8* ldsC = lA;  // 128p x 128i fp8 tile
  const int rbl = wr * 64 + ((lane >> 4) << 2);  // local i
  const int cbl = wc * 64 + (lane & 15);         // local p
  const float SCL = 0.0625f * 1.44269504089f;    // exp(x) = exp2(x*log2e)
  float ps[4][4] = {};
#pragma unroll
  for (int mi = 0; mi < 4; mi++)
#pragma unroll
    for (int ni = 0; ni < 4; ni++) {
      int pl = cbl + ni * 16, ib = rbl + mi * 16;
      float e0 = exp2f(acc[mi][ni][0] * SCL);
      float e1 = exp2f(acc[mi][ni][1] * SCL);
      float e2 = exp2f(acc[mi][ni][2] * SCL);
      float e3 = exp2f(acc[mi][ni][3] * SCL);
      ps[mi][0] += e0; ps[mi][1] += e1; ps[mi][2] += e2; ps[mi][3] += e3;
      *(unsigned*)(ldsC + pl * 128 + (ib ^ ((pl & 7) << 4))) = pk4(e0, e1, e2, e3);
    }
#pragma unroll
  for (int mi = 0; mi < 4; mi++)
#pragma unroll
    for (int j = 0; j < 4; j++) {
      float v = ps[mi][j];
      v += __shfl_xor(v, 1); v += __shfl_xor(v, 2);
      v += __shfl_xor(v, 4); v += __shfl_xor(v, 8);
      if ((lane & 15) == 0)
        partials[(size_t)(z * 1024 + m0 + rbl + mi * 16 + j) * 16 + pb * 2 + wc] = v;
    }
  __syncthreads();
#pragma unroll
  for (int ph = 0; ph < 4; ph++) {
    int pl = ph * 32 + (t >> 3), ich = (t & 7) * 16;
    uint4 v = *(const uint4*)(ldsC + pl * 128 + (ich ^ ((pl & 7) << 4)));
    *(uint4*)(Ez + (size_t)(n0 + pl) * 1024 + m0 + ich) = v;
  }
}

// ---- Qt8[c][i] = fp8(Q[i][c] * (1024/L[i])): transpose + rinv fold, with
// the partials reduction (rinv) fused in.
__global__ __launch_bounds__(256) void qt8(
    const u8* __restrict__ Q8, const float* __restrict__ partials, u8* __restrict__ Qt) {
  __shared__ u8 tile[64][260];
  __shared__ float rv[64];
  const int z = blockIdx.y, i0 = blockIdx.x * 64;
  const u8* src = Q8 + (size_t)z * 262144;
  u8* dst = Qt + (size_t)z * 262144;
  const int t = threadIdx.x;
#pragma unroll
  for (int q = 0; q < 4; q++) {
    uint4 v = *(const uint4*)(src + (size_t)(i0 + (t >> 2)) * 256 + (t & 3) * 64 + q * 16);
    *(uint4*)(&tile[t >> 2][(t & 3) * 64 + q * 16]) = v;
  }
  if (t < 64) {
    const float4* p = (const float4*)(partials + (size_t)(z * 1024 + i0 + t) * 16);
    float4 a = p[0], b = p[1], c = p[2], d = p[3];
    float s = ((a.x + a.y) + (a.z + a.w)) + ((b.x + b.y) + (b.z + b.w)) +
              ((c.x + c.y) + (c.z + c.w)) + ((d.x + d.y) + (d.z + d.w));
    rv[t] = 1024.0f / s;
  }
  __syncthreads();
#pragma unroll
  for (int q = 0; q < 4; q++) {
    unsigned wd[4];
#pragma unroll
    for (int d = 0; d < 4; d++) {
      float f[4];
#pragma unroll
      for (int e = 0; e < 4; e++) {
        int i = q * 16 + d * 4 + e;
        f[e] = f8df(tile[i][t]) * rv[i];
      }
      wd[d] = pk4(f[0], f[1], f[2], f[3]);
    }
    uint4 v = {wd[0], wd[1], wd[2], wd[3]};
    *(uint4*)(dst + (size_t)t * 1024 + i0 + q * 16) = v;
  }
}

// ---- FUSED GEMM-O + GEMM-F, counted-vmcnt pipelined (T3/T4).
// phase 1: ob[p,c] = (1/1024)*sum_i Et[p,i]*Qt[c,i] -> bf16 swizzled LDS tile
// phase 2: acc2[p,d] = sum_c ob[p,c]*woutT[d,c]
// epilogue: spill acc2 f32 -> LDS, coalesced x + store.
// Grid (z=32, m=8): id%8 = z%8 -> Qt panel L2-resident per XCD.
__global__ __launch_bounds__(512) void gemm_of(
    const u8* __restrict__ Et, const u8* __restrict__ Qt,
    const u16* __restrict__ woutT, const float* __restrict__ x,
    float* __restrict__ C) {
  __shared__ char smem[131072];
  const int z = blockIdx.x;
  const int m0 = blockIdx.y * 128;
  const u8* Az = Et + (size_t)z * 1048576;
  const u8* Bz = Qt + (size_t)z * 262144;
  const int t = threadIdx.x, lane = t & 63;
  const int w = t >> 6, wr = w >> 2, wc = w & 3;
  f32x4 acc[4][4] = {};

#define O8_STAGE(B, K0)                                                       \
  {                                                                           \
    u8* la_ = (u8*)smem + (B) * 16384;                                        \
    u8* lb_ = (u8*)smem + 32768 + (B) * 32768;                                \
    _Pragma("unroll") for (int ch = 0; ch < 2; ch++) {                        \
      int flat = ch * 512 + t, row = flat >> 3, slot = flat & 7;              \
      GLD16(Az + (size_t)(m0 + row) * 1024 + (K0) + (slot ^ sig(row)) * 16,   \
            la_ + flat * 16);                                                 \
    }                                                                         \
    _Pragma("unroll") for (int ch = 0; ch < 4; ch++) {                        \
      int flat = ch * 512 + t, row = flat >> 3, slot = flat & 7;              \
      GLD16(Bz + (size_t)row * 1024 + (K0) + (slot ^ sig(row)) * 16,          \
            lb_ + flat * 16);                                                 \
    }                                                                         \
  }

  O8_STAGE(0, 0);
  for (int it = 0; it < 8; it++) {
    if (it < 7) {
      O8_STAGE((it + 1) & 1, (it + 1) * 128);
      VMW(6);               // wait only the 6 loads of buf[it&1]; next 6 in flight
    } else {
      VMW(0);
    }
    __builtin_amdgcn_sched_barrier(0);
    __builtin_amdgcn_s_barrier();      // buf[it&1] ready for all waves
    __builtin_amdgcn_sched_barrier(0);
    const u8* la = (const u8*)smem + (it & 1) * 16384;
    const u8* lb = (const u8*)smem + 32768 + (it & 1) * 32768;
#pragma unroll
    for (int kk = 0; kk < 4; kk++) {
      i64 af[4], bfv[4];
      int koff = kk * 32 + (lane >> 4) * 8;
#pragma unroll
      for (int mi = 0; mi < 4; mi++) {
        int m = wr * 64 + mi * 16 + (lane & 15);
        af[mi] = *(const i64*)(la + m * 128 + (koff ^ (sig(m) << 4)));
      }
#pragma unroll
      for (int ni = 0; ni < 4; ni++) {
        int n = wc * 64 + ni * 16 + (lane & 15);
        bfv[ni] = *(const i64*)(lb + n * 128 + (koff ^ (sig(n) << 4)));
      }
#pragma unroll
      for (int mi = 0; mi < 4; mi++)
#pragma unroll
        for (int ni = 0; ni < 4; ni++)
          acc[mi][ni] = __builtin_amdgcn_mfma_f32_16x16x32_fp8_fp8(af[mi], bfv[ni], acc[mi][ni], 0, 0, 0);
    }
    __builtin_amdgcn_s_barrier();      // all waves done reading buf[it&1]
  }
#undef O8_STAGE

#define W_STAGE(B, K0)                                                        \
  {                                                                           \
    u16* wb_ = (u16*)(smem + 65536 + (B) * 32768);                            \
    _Pragma("unroll") for (int ch = 0; ch < 4; ch++) {                        \
      int flat = ch * 512 + t, row = flat >> 3, slot = flat & 7;              \
      GLD16(woutT + (size_t)row * 256 + (K0) + (slot ^ sig(row)) * 8,         \
            (u8*)wb_ + flat * 16);                                            \
    }                                                                         \
  }
  // transition: issue W0 loads, spill acc -> bf16 ob tile [0,64K)
  W_STAGE(0, 0);
  {
    const int rbl = wr * 64 + ((lane >> 4) << 2);
    const int cbl = wc * 64 + (lane & 15);
#pragma unroll
    for (int mi = 0; mi < 4; mi++)
#pragma unroll
      for (int ni = 0; ni < 4; ni++)
#pragma unroll
        for (int j = 0; j < 4; j++) {
          int pl = rbl + mi * 16 + j, c = cbl + ni * 16;
          int byteoff = (pl * 512 + c * 2) ^ ((pl & 7) << 4);
          *(u16*)(smem + byteoff) = f2bf(acc[mi][ni][j] * (1.0f / 1024.0f));
        }
  }
  asm volatile("s_waitcnt lgkmcnt(0)" ::: "memory");  // ob writes drained (not vmcnt!)
  __builtin_amdgcn_sched_barrier(0);
  __builtin_amdgcn_s_barrier();
  __builtin_amdgcn_sched_barrier(0);

  f32x4 acc2[4][4] = {};
  for (int it2 = 0; it2 < 4; it2++) {
    if (it2 < 3) {
      W_STAGE((it2 + 1) & 1, (it2 + 1) * 64);
      VMW(4);              // wait the 4 loads of Wbuf[it2&1]; next 4 in flight
    } else {
      VMW(0);
    }
    __builtin_amdgcn_sched_barrier(0);
    __builtin_amdgcn_s_barrier();
    __builtin_amdgcn_sched_barrier(0);
    const u16* lb = (const u16*)(smem + 65536 + (it2 & 1) * 32768);
#pragma unroll
    for (int kk = 0; kk < 2; kk++) {
      bf16x8 af[4], bfr[4];
#pragma unroll
      for (int mi = 0; mi < 4; mi++) {
        int m = wr * 64 + mi * 16 + (lane & 15);
        int kg = it2 * 64 + kk * 32 + (lane >> 4) * 8;
        af[mi] = *(const bf16x8*)(smem + ((m * 512 + kg * 2) ^ ((m & 7) << 4)));
      }
#pragma unroll
      for (int ni = 0; ni < 4; ni++) {
        int n = wc * 64 + ni * 16 + (lane & 15);
        bfr[ni] = *(const bf16x8*)(lb + n * 64 + ((kk * 32 + (lane >> 4) * 8) ^ (sig(n) << 3)));
      }
#pragma unroll
      for (int mi = 0; mi < 4; mi++)
#pragma unroll
        for (int ni = 0; ni < 4; ni++)
          acc2[mi][ni] = __builtin_amdgcn_mfma_f32_16x16x32_bf16(af[mi], bfr[ni], acc2[mi][ni], 0, 0, 0);
    }
    __builtin_amdgcn_s_barrier();
  }
#undef W_STAGE

  // epilogue: spill acc2 f32 to full 128KB LDS, then coalesced x-add-store
  {
    const int rbl = wr * 64 + ((lane >> 4) << 2);
    const int cbl = wc * 64 + (lane & 15);
#pragma unroll
    for (int mi = 0; mi < 4; mi++)
#pragma unroll
      for (int ni = 0; ni < 4; ni++)
#pragma unroll
        for (int j = 0; j < 4; j++) {
          int pl = rbl + mi * 16 + j, c = cbl + ni * 16;
          *(float*)(smem + ((pl * 1024 + c * 4) ^ ((pl & 7) << 4))) = acc2[mi][ni][j];
        }
    __syncthreads();
    const size_t base = (size_t)(z * 1024 + m0) * 256;
#pragma unroll
    for (int pi = 0; pi < 16; pi++) {
      int flat = pi * 512 + t;
      int row = flat >> 6, ch = flat & 63;
      f32x4 a = *(const f32x4*)(smem + row * 1024 + ((ch * 16) ^ ((row & 7) << 4)));
      const float4 xv = *(const float4*)(x + base + (size_t)flat * 4);
      float4 o;
      o.x = a[0] + xv.x; o.y = a[1] + xv.y; o.z = a[2] + xv.z; o.w = a[3] + xv.w;
      *(float4*)(C + base + (size_t)flat * 4) = o;
    }
  }
}

extern "C" void kernel_launch(void* const* d_in, const int* in_sizes, int n_in,
                              void* d_out, int out_size, void* d_ws, size_t ws_size,
                              hipStream_t stream) {
  (void)in_sizes; (void)n_in; (void)out_size; (void)ws_size;
  const float* x = (const float*)d_in[0];
  const float* gamma = (const float*)d_in[1];
  const float* beta = (const float*)d_in[2];
  const float* wqkv = (const float*)d_in[3];
  const float* wout = (const float*)d_in[4];
  float* outp = (float*)d_out;

  char* ws = (char*)d_ws;
  const size_t MB = 1024 * 1024;
  u16* wtT = (u16*)(ws + 0);                     // 128K
  u16* woutT = (u16*)(ws + (128 << 10));         // 128K
  float* partials = (float*)(ws + (512 << 10));  // 2M
  u8* Q8 = (u8*)(ws + 3 * MB);                   // 8M  fp8 Tt layout (Q rows flat)
  u8* Kt8 = (u8*)(ws + 12 * MB);                 // 8M  fp8 [z][1024][256]
  u8* Qt = (u8*)(ws + 21 * MB);                  // 8M  fp8 [z][256][1024]
  u8* Et = (u8*)(ws + 30 * MB);                  // 32M fp8 [z][p][i]

  combine_w<<<256, 256, 0, stream>>>(wqkv, wout, wtT, woutT);
  gnT<<<512, 512, 0, stream>>>(x, gamma, beta, wtT, Q8, Kt8);
  gemm_s8<<<dim3(32, 64), 256, 0, stream>>>(Q8, Kt8, Et, partials);
  qt8<<<dim3(16, 32), 256, 0, stream>>>(Q8, partials, Qt);
  gemm_of<<<dim3(32, 8), 512, 0, stream>>>(Et, Qt, woutT, x, outp);
}

// Round 9
// 90.126 us; speedup vs baseline: 1.1404x; 1.0137x over previous
//
#include <hip/hip_runtime.h>

typedef unsigned short u16;
typedef unsigned char u8;
typedef long long i64;
typedef __bf16 bf16x8 __attribute__((ext_vector_type(8)));
typedef float f32x4 __attribute__((ext_vector_type(4)));
typedef u16 u16x8 __attribute__((ext_vector_type(8)));

#define GLD16(g, l) __builtin_amdgcn_global_load_lds( \
    (const __attribute__((address_space(1))) void*)(g), \
    (__attribute__((address_space(3))) void*)(l), 16, 0, 0)
// counted vmcnt wait (N literal) -- lets prefetch loads stay in flight across barriers
#define VMW(N) asm volatile("s_waitcnt vmcnt(" #N ")" ::: "memory")
#define SCHB __builtin_amdgcn_sched_barrier(0)
#define SBAR __builtin_amdgcn_s_barrier()

__device__ __forceinline__ float bf2f(u16 u) {
  return __uint_as_float(((unsigned)u) << 16);
}
__device__ __forceinline__ u16 f2bf(float f) {  // RNE
  unsigned u = __float_as_uint(f);
  return (u16)((u + 0x7fffu + ((u >> 16) & 1u)) >> 16);
}
// ---- software fp8 e4m3fn fallback codec ----
__device__ __forceinline__ u8 f8e_sw(float v) {
  unsigned u = __float_as_uint(v);
  unsigned s = (u >> 24) & 0x80u;
  u &= 0x7fffffffu;
  if (u < 0x3c000000u) return (u8)s;
  int b = (int)((u + 0x7FFFFu + ((u >> 20) & 1u)) >> 20) - 960;
  b = b < 8 ? 8 : (b > 126 ? 126 : b);
  return (u8)(b | s);
}
__device__ __forceinline__ float f8d_sw(u8 b) {
  if (!(b & 0x7f)) return 0.0f;
  float v = __uint_as_float((((unsigned)(b & 0x7fu)) << 20) + 0x3C000000u);
  return (b & 0x80u) ? -v : v;
}
// ---- hardware fp8 codec (gfx950) with sw fallback ----
__device__ __forceinline__ unsigned pk4(float a, float b, float c, float d) {
#if __has_builtin(__builtin_amdgcn_cvt_pk_fp8_f32)
  int r = __builtin_amdgcn_cvt_pk_fp8_f32(a, b, 0, false);
  r = __builtin_amdgcn_cvt_pk_fp8_f32(c, d, r, true);
  return (unsigned)r;
#else
  return (unsigned)f8e_sw(a) | ((unsigned)f8e_sw(b) << 8) |
         ((unsigned)f8e_sw(c) << 16) | ((unsigned)f8e_sw(d) << 24);
#endif
}
__device__ __forceinline__ float f8df(u8 b) {
#if __has_builtin(__builtin_amdgcn_cvt_f32_fp8)
  return __builtin_amdgcn_cvt_f32_fp8((int)b, 0);
#else
  return f8d_sw(b);
#endif
}
// 16B-slot swizzle keys
__device__ __forceinline__ int sig(int r) { return (r ^ (r >> 3)) & 7; }   // 8-slot rows
__device__ __forceinline__ int wkey(int r) { return (r ^ (r >> 2)) & 3; }  // 4-slot rows

// ---- weight prep: wtT[d][c] = ((Wq+Wk+Wv)/3)[c][d], woutT[d][c] = w_out[c][d]
__global__ void combine_w(const float* __restrict__ wqkv, const float* __restrict__ wout,
                          u16* __restrict__ wtT, u16* __restrict__ woutT) {
  int c = blockIdx.x, d = threadIdx.x;
  float t = (wqkv[c * 768 + d] + wqkv[c * 768 + 256 + d] + wqkv[c * 768 + 512 + d]) * (1.0f / 3.0f);
  wtT[d * 256 + c] = f2bf(t);
  woutT[d * 256 + c] = f2bf(wout[c * 256 + d]);
}

// ---- fused GroupNorm + GEMM-T, double-buffered. Tile 64x256, 8 waves.
__global__ __launch_bounds__(512) void gnT(
    const float* __restrict__ x, const float* __restrict__ gamma,
    const float* __restrict__ beta, const u16* __restrict__ wtT,
    u8* __restrict__ Q8, u8* __restrict__ Kt8) {
  __shared__ u16 lA[2][64 * 64];
  __shared__ u16 lB[2][256 * 64];
  const int m0 = blockIdx.x * 64;   // global pixel base (single batch per block)
  const int z = m0 >> 10;
  const int t = threadIdx.x, lane = t & 63;
  const int w = t >> 6, wr = w >> 2, wc = w & 3;
  f32x4 acc[2][4] = {};

#define GNT_STAGE(B, K0)                                                        \
  {                                                                             \
    _Pragma("unroll") for (int ch = 0; ch < 4; ch++) {                          \
      int flat = ch * 512 + t, row = flat >> 3, slot = flat & 7;                \
      GLD16(wtT + (size_t)row * 256 + (K0) + (slot ^ sig(row)) * 8,             \
            lB[B] + flat * 8);                                                  \
    }                                                                           \
    int row = t >> 3, grp = t & 7;                                              \
    const float* xp = x + (size_t)(m0 + row) * 256 + (K0) + grp * 8;            \
    float4 a = *(const float4*)xp, b = *(const float4*)(xp + 4);                \
    float mu = (a.x + a.y + a.z + a.w + b.x + b.y + b.z + b.w) * 0.125f;        \
    float d0 = a.x - mu, d1 = a.y - mu, d2 = a.z - mu, d3 = a.w - mu;           \
    float d4 = b.x - mu, d5 = b.y - mu, d6 = b.z - mu, d7 = b.w - mu;           \
    float var = (d0 * d0 + d1 * d1 + d2 * d2 + d3 * d3 +                        \
                 d4 * d4 + d5 * d5 + d6 * d6 + d7 * d7) * 0.125f;               \
    float rs = rsqrtf(var + 1e-6f);                                             \
    const float4 g0 = *(const float4*)(gamma + (K0) + grp * 8);                 \
    const float4 g1 = *(const float4*)(gamma + (K0) + grp * 8 + 4);             \
    const float4 e0 = *(const float4*)(beta + (K0) + grp * 8);                  \
    const float4 e1 = *(const float4*)(beta + (K0) + grp * 8 + 4);              \
    u16x8 o;                                                                    \
    o[0] = f2bf(g0.x * (d0 * rs) + e0.x); o[1] = f2bf(g0.y * (d1 * rs) + e0.y); \
    o[2] = f2bf(g0.z * (d2 * rs) + e0.z); o[3] = f2bf(g0.w * (d3 * rs) + e0.w); \
    o[4] = f2bf(g1.x * (d4 * rs) + e1.x); o[5] = f2bf(g1.y * (d5 * rs) + e1.y); \
    o[6] = f2bf(g1.z * (d6 * rs) + e1.z); o[7] = f2bf(g1.w * (d7 * rs) + e1.w); \
    *(u16x8*)(lA[B] + row * 64 + (grp ^ sig(row)) * 8) = o;                     \
  }

  GNT_STAGE(0, 0);
  __syncthreads();
  for (int it = 0; it < 4; it++) {
    if (it < 3) { GNT_STAGE((it + 1) & 1, (it + 1) * 64); }
    const u16* la = lA[it & 1];
    const u16* lb = lB[it & 1];
#pragma unroll
    for (int kk = 0; kk < 2; kk++) {
      bf16x8 af[2], bfr[4];
#pragma unroll
      for (int mi = 0; mi < 2; mi++) {
        int m = wr * 32 + mi * 16 + (lane & 15);
        af[mi] = *(const bf16x8*)(la + m * 64 + ((kk * 32 + (lane >> 4) * 8) ^ (sig(m) << 3)));
      }
#pragma unroll
      for (int ni = 0; ni < 4; ni++) {
        int n = wc * 64 + ni * 16 + (lane & 15);
        bfr[ni] = *(const bf16x8*)(lb + n * 64 + ((kk * 32 + (lane >> 4) * 8) ^ (sig(n) << 3)));
      }
#pragma unroll
      for (int mi = 0; mi < 2; mi++)
#pragma unroll
        for (int ni = 0; ni < 4; ni++)
          acc[mi][ni] = __builtin_amdgcn_mfma_f32_16x16x32_bf16(af[mi], bfr[ni], acc[mi][ni], 0, 0, 0);
    }
    __syncthreads();
  }

  const int rb = m0 + wr * 32 + ((lane >> 4) << 2);  // global pixel, %4 == 0
  const int cb = wc * 64 + (lane & 15);
  u8* kt = (u8*)lB[0];          // 16KB: Kt8 repack [1024 rows][16B]
  u8* qtile = (u8*)lB[1];       // 20KB: Q8 repack [256 c][80B stride, 64B data]
#pragma unroll
  for (int mi = 0; mi < 2; mi++)
#pragma unroll
    for (int ni = 0; ni < 4; ni++) {
      int P0 = rb + mi * 16, c = cb + ni * 16;
      int pl = P0 - m0;                     // 0..63, %4==0
      unsigned pk = pk4(acc[mi][ni][0], acc[mi][ni][1], acc[mi][ni][2], acc[mi][ni][3]);
#pragma unroll
      for (int j = 0; j < 4; j++)
        kt[(j * 256 + c) * 16 + (pl >> 2)] = (u8)(pk >> (8 * j));
      *(unsigned*)(qtile + c * 80 + pl) = pk;
    }
  __syncthreads();
  const int ckb = (m0 & 1023) >> 2;
  u8* Kz = Kt8 + (size_t)z * 262144;
  u8* Qz = Q8 + (size_t)z * 262144;
#pragma unroll
  for (int r2 = 0; r2 < 2; r2++) {
    int r = t * 2 + r2;
    uint4 v = *(const uint4*)(kt + r * 16);
    *(uint4*)(Kz + (size_t)r * 256 + ckb) = v;
  }
#pragma unroll
  for (int ph = 0; ph < 2; ph++) {
    int idx = ph * 512 + t, c = idx >> 2, q = idx & 3;
    uint4 v = *(const uint4*)(qtile + c * 80 + q * 16);
    *(uint4*)(Qz + (size_t)c * 1024 + (m0 & 1023) + q * 16) = v;
  }
#undef GNT_STAGE
}

// ---- GEMM-S (fp8): Et[p,i] = fp8(exp((Q@K)[i,p]/16)) + row partial sums.
// 2-stage BK=128 dbuf, counted vmcnt: buf1 staging hides under buf0 compute.
__global__ __launch_bounds__(256) void gemm_s8(
    const u8* __restrict__ Q8, const u8* __restrict__ Kt8,
    u8* __restrict__ Et, float* __restrict__ partials) {
  __shared__ u8 lA[2][128 * 128];
  __shared__ u8 lB[2][128 * 128];
  const int z = blockIdx.x;
  const int mb = blockIdx.y & 7, pb = blockIdx.y >> 3;
  const u8* Az = Q8 + (size_t)z * 262144;
  const u8* Bz = Kt8 + (size_t)z * 262144;
  u8* Ez = Et + (size_t)z * 1048576;
  const int m0 = mb * 128, n0 = pb * 128;
  const int t = threadIdx.x, lane = t & 63;
  const int wr = (t >> 6) >> 1, wc = (t >> 6) & 1;
  f32x4 acc[4][4] = {};

#define S8_STAGE(B, K0)                                                       \
  {                                                                           \
    _Pragma("unroll") for (int ch = 0; ch < 4; ch++) {                        \
      int flat = ch * 256 + t, row = flat >> 3, slot = flat & 7;              \
      GLD16(Az + (size_t)(m0 + row) * 256 + (K0) + (slot ^ sig(row)) * 16,    \
            lA[B] + flat * 16);                                               \
    }                                                                         \
    _Pragma("unroll") for (int ch = 0; ch < 4; ch++) {                        \
      int flat = ch * 256 + t, row = flat >> 3, slot = flat & 7;              \
      GLD16(Bz + (size_t)(n0 + row) * 256 + (K0) + (slot ^ sig(row)) * 16,    \
            lB[B] + flat * 16);                                               \
    }                                                                         \
  }
#define S8_COMP(LA, LB)                                                       \
  _Pragma("unroll") for (int kk = 0; kk < 4; kk++) {                          \
    i64 af[4], bfv[4];                                                        \
    int koff = kk * 32 + (lane >> 4) * 8;                                     \
    _Pragma("unroll") for (int mi = 0; mi < 4; mi++) {                        \
      int m = wr * 64 + mi * 16 + (lane & 15);                                \
      af[mi] = *(const i64*)((LA) + m * 128 + (koff ^ (sig(m) << 4)));        \
    }                                                                         \
    _Pragma("unroll") for (int ni = 0; ni < 4; ni++) {                        \
      int n = wc * 64 + ni * 16 + (lane & 15);                                \
      bfv[ni] = *(const i64*)((LB) + n * 128 + (koff ^ (sig(n) << 4)));       \
    }                                                                         \
    _Pragma("unroll") for (int mi = 0; mi < 4; mi++)                          \
      _Pragma("unroll") for (int ni = 0; ni < 4; ni++)                        \
        acc[mi][ni] = __builtin_amdgcn_mfma_f32_16x16x32_fp8_fp8(             \
            af[mi], bfv[ni], acc[mi][ni], 0, 0, 0);                           \
  }

  S8_STAGE(0, 0);
  S8_STAGE(1, 128);
  VMW(8); SCHB; SBAR; SCHB;
  __builtin_amdgcn_s_setprio(1);
  S8_COMP(lA[0], lB[0]);
  __builtin_amdgcn_s_setprio(0);
  VMW(0); SCHB; SBAR; SCHB;
  __builtin_amdgcn_s_setprio(1);
  S8_COMP(lA[1], lB[1]);
  __builtin_amdgcn_s_setprio(0);
  __syncthreads();
#undef S8_STAGE
#undef S8_COMP

  u8* ldsC = lA[0];  // 128p x 128i fp8 tile (16KB)
  const int rbl = wr * 64 + ((lane >> 4) << 2);  // local i
  const int cbl = wc * 64 + (lane & 15);         // local p
  const float SCL = 0.0625f * 1.44269504089f;    // exp(x) = exp2(x*log2e)
  float ps[4][4] = {};
#pragma unroll
  for (int mi = 0; mi < 4; mi++)
#pragma unroll
    for (int ni = 0; ni < 4; ni++) {
      int pl = cbl + ni * 16, ib = rbl + mi * 16;
      float e0 = exp2f(acc[mi][ni][0] * SCL);
      float e1 = exp2f(acc[mi][ni][1] * SCL);
      float e2 = exp2f(acc[mi][ni][2] * SCL);
      float e3 = exp2f(acc[mi][ni][3] * SCL);
      ps[mi][0] += e0; ps[mi][1] += e1; ps[mi][2] += e2; ps[mi][3] += e3;
      *(unsigned*)(ldsC + pl * 128 + (ib ^ ((pl & 7) << 4))) = pk4(e0, e1, e2, e3);
    }
#pragma unroll
  for (int mi = 0; mi < 4; mi++)
#pragma unroll
    for (int j = 0; j < 4; j++) {
      float v = ps[mi][j];
      v += __shfl_xor(v, 1); v += __shfl_xor(v, 2);
      v += __shfl_xor(v, 4); v += __shfl_xor(v, 8);
      if ((lane & 15) == 0)
        partials[(size_t)(z * 1024 + m0 + rbl + mi * 16 + j) * 16 + pb * 2 + wc] = v;
    }
  __syncthreads();
#pragma unroll
  for (int ph = 0; ph < 4; ph++) {
    int pl = ph * 32 + (t >> 3), ich = (t & 7) * 16;
    uint4 v = *(const uint4*)(ldsC + pl * 128 + (ich ^ ((pl & 7) << 4)));
    *(uint4*)(Ez + (size_t)(n0 + pl) * 1024 + m0 + ich) = v;
  }
}

// ---- Qt8[c][i] = fp8(Q[i][c] * (1024/L[i])): transpose + rinv fold.
__global__ __launch_bounds__(256) void qt8(
    const u8* __restrict__ Q8, const float* __restrict__ partials, u8* __restrict__ Qt) {
  __shared__ u8 tile[64][260];
  __shared__ float rv[64];
  const int z = blockIdx.y, i0 = blockIdx.x * 64;
  const u8* src = Q8 + (size_t)z * 262144;
  u8* dst = Qt + (size_t)z * 262144;
  const int t = threadIdx.x;
#pragma unroll
  for (int q = 0; q < 4; q++) {
    uint4 v = *(const uint4*)(src + (size_t)(i0 + (t >> 2)) * 256 + (t & 3) * 64 + q * 16);
    *(uint4*)(&tile[t >> 2][(t & 3) * 64 + q * 16]) = v;
  }
  if (t < 64) {
    const float4* p = (const float4*)(partials + (size_t)(z * 1024 + i0 + t) * 16);
    float4 a = p[0], b = p[1], c = p[2], d = p[3];
    float s = ((a.x + a.y) + (a.z + a.w)) + ((b.x + b.y) + (b.z + b.w)) +
              ((c.x + c.y) + (c.z + c.w)) + ((d.x + d.y) + (d.z + d.w));
    rv[t] = 1024.0f / s;
  }
  __syncthreads();
#pragma unroll
  for (int q = 0; q < 4; q++) {
    unsigned wd[4];
#pragma unroll
    for (int d = 0; d < 4; d++) {
      float f[4];
#pragma unroll
      for (int e = 0; e < 4; e++) {
        int i = q * 16 + d * 4 + e;
        f[e] = f8df(tile[i][t]) * rv[i];
      }
      wd[d] = pk4(f[0], f[1], f[2], f[3]);
    }
    uint4 v = {wd[0], wd[1], wd[2], wd[3]};
    *(uint4*)(dst + (size_t)t * 1024 + i0 + q * 16) = v;
  }
}

// ---- FUSED GEMM-O + GEMM-F, 64x256 tile, 80KB LDS -> 2 blocks/CU.
// phase 1: ob[64p,256c] = (1/1024)*Et[64,1024] x Qt[256,1024]^T (fp8, vmcnt(5))
// phase 2: acc2[64p,256d] = ob x woutT^T (bf16, K-step 32, vmcnt(2))
// epilogue: f32 spill -> coalesced x-add-store.
// LDS map: p1: A dbuf [0,16K), B dbuf [16K,80K). p2: ob [0,32K), W dbuf [32K,64K).
// epi: f32 tile [0,64K).
__global__ __launch_bounds__(512, 4) void gemm_of(
    const u8* __restrict__ Et, const u8* __restrict__ Qt,
    const u16* __restrict__ woutT, const float* __restrict__ x,
    float* __restrict__ C) {
  __shared__ char smem[81920];
  const int z = blockIdx.x;
  const int m0 = blockIdx.y * 64;
  const u8* Az = Et + (size_t)z * 1048576;
  const u8* Bz = Qt + (size_t)z * 262144;
  const int t = threadIdx.x, lane = t & 63;
  const int w = t >> 6, wr = w >> 2, wc = w & 3;  // wr 0..1, wc 0..3
  f32x4 acc[2][4] = {};

#define O8_STAGE(B, K0)                                                       \
  {                                                                           \
    u8* la_ = (u8*)smem + (B) * 8192;                                         \
    u8* lb_ = (u8*)smem + 16384 + (B) * 32768;                                \
    {                                                                         \
      int row = t >> 3, slot = t & 7;                                         \
      GLD16(Az + (size_t)(m0 + row) * 1024 + (K0) + (slot ^ sig(row)) * 16,   \
            la_ + t * 16);                                                    \
    }                                                                         \
    _Pragma("unroll") for (int ch = 0; ch < 4; ch++) {                        \
      int flat = ch * 512 + t, row = flat >> 3, slot = flat & 7;              \
      GLD16(Bz + (size_t)row * 1024 + (K0) + (slot ^ sig(row)) * 16,          \
            lb_ + flat * 16);                                                 \
    }                                                                         \
  }

  O8_STAGE(0, 0);
  for (int it = 0; it < 8; it++) {
    if (it < 7) {
      O8_STAGE((it + 1) & 1, (it + 1) * 128);
      VMW(5);
    } else {
      VMW(0);
    }
    SCHB; SBAR; SCHB;
    const u8* la = (const u8*)smem + (it & 1) * 8192;
    const u8* lb = (const u8*)smem + 16384 + (it & 1) * 32768;
    __builtin_amdgcn_s_setprio(1);
#pragma unroll
    for (int kk = 0; kk < 4; kk++) {
      i64 af[2], bfv[4];
      int koff = kk * 32 + (lane >> 4) * 8;
#pragma unroll
      for (int mi = 0; mi < 2; mi++) {
        int m = wr * 32 + mi * 16 + (lane & 15);
        af[mi] = *(const i64*)(la + m * 128 + (koff ^ (sig(m) << 4)));
      }
#pragma unroll
      for (int ni = 0; ni < 4; ni++) {
        int n = wc * 64 + ni * 16 + (lane & 15);
        bfv[ni] = *(const i64*)(lb + n * 128 + (koff ^ (sig(n) << 4)));
      }
#pragma unroll
      for (int mi = 0; mi < 2; mi++)
#pragma unroll
        for (int ni = 0; ni < 4; ni++)
          acc[mi][ni] = __builtin_amdgcn_mfma_f32_16x16x32_fp8_fp8(af[mi], bfv[ni], acc[mi][ni], 0, 0, 0);
    }
    __builtin_amdgcn_s_setprio(0);
    SBAR;
  }
#undef O8_STAGE

#define W_STAGE(B, K0)                                                        \
  {                                                                           \
    u8* wb_ = (u8*)smem + 32768 + (B) * 16384;                                \
    _Pragma("unroll") for (int ch = 0; ch < 2; ch++) {                        \
      int flat = ch * 512 + t, row = flat >> 2, slot = flat & 3;              \
      GLD16(woutT + (size_t)row * 256 + (K0) + (slot ^ wkey(row)) * 8,        \
            wb_ + flat * 16);                                                 \
    }                                                                         \
  }
  // transition: issue W0, spill acc -> bf16 ob tile [0,32K)
  W_STAGE(0, 0);
  {
#pragma unroll
    for (int mi = 0; mi < 2; mi++)
#pragma unroll
      for (int ni = 0; ni < 4; ni++)
#pragma unroll
        for (int j = 0; j < 4; j++) {
          int pl = wr * 32 + mi * 16 + ((lane >> 4) << 2) + j;
          int c = wc * 64 + ni * 16 + (lane & 15);
          int byteoff = (pl * 512 + c * 2) ^ ((pl & 7) << 4);
          *(u16*)(smem + byteoff) = f2bf(acc[mi][ni][j] * (1.0f / 1024.0f));
        }
  }
  asm volatile("s_waitcnt lgkmcnt(0)" ::: "memory");
  SCHB; SBAR; SCHB;

  f32x4 acc2[2][4] = {};
  for (int it2 = 0; it2 < 8; it2++) {
    if (it2 < 7) {
      W_STAGE((it2 + 1) & 1, (it2 + 1) * 32);
      VMW(2);
    } else {
      VMW(0);
    }
    SCHB; SBAR; SCHB;
    const u8* wb = (const u8*)smem + 32768 + (it2 & 1) * 16384;
    __builtin_amdgcn_s_setprio(1);
    {
      bf16x8 af2[2], bfr[4];
#pragma unroll
      for (int mi = 0; mi < 2; mi++) {
        int m = wr * 32 + mi * 16 + (lane & 15);
        int kg = (it2 * 32 + (lane >> 4) * 8) * 2;
        af2[mi] = *(const bf16x8*)(smem + ((m * 512 + kg) ^ ((m & 7) << 4)));
      }
#pragma unroll
      for (int ni = 0; ni < 4; ni++) {
        int n = wc * 64 + ni * 16 + (lane & 15);
        int s = lane >> 4;
        bfr[ni] = *(const bf16x8*)(wb + n * 64 + (s ^ wkey(n)) * 16);
      }
#pragma unroll
      for (int mi = 0; mi < 2; mi++)
#pragma unroll
        for (int ni = 0; ni < 4; ni++)
          acc2[mi][ni] = __builtin_amdgcn_mfma_f32_16x16x32_bf16(af2[mi], bfr[ni], acc2[mi][ni], 0, 0, 0);
    }
    __builtin_amdgcn_s_setprio(0);
    SBAR;
  }
#undef W_STAGE

  // epilogue: spill acc2 f32 to [0,64K), then coalesced x-add-store
  {
#pragma unroll
    for (int mi = 0; mi < 2; mi++)
#pragma unroll
      for (int ni = 0; ni < 4; ni++)
#pragma unroll
        for (int j = 0; j < 4; j++) {
          int pl = wr * 32 + mi * 16 + ((lane >> 4) << 2) + j;
          int c = wc * 64 + ni * 16 + (lane & 15);
          *(float*)(smem + ((pl * 1024 + c * 4) ^ ((pl & 7) << 4))) = acc2[mi][ni][j];
        }
    __syncthreads();
    const size_t base = ((size_t)z * 1024 + m0) * 256;
#pragma unroll
    for (int pi = 0; pi < 8; pi++) {
      int f4 = pi * 512 + t;
      int row = f4 >> 6, ch = f4 & 63;
      f32x4 a = *(const f32x4*)(smem + row * 1024 + ((ch * 16) ^ ((row & 7) << 4)));
      const float4 xv = *(const float4*)(x + base + (size_t)f4 * 4);
      float4 o;
      o.x = a[0] + xv.x; o.y = a[1] + xv.y; o.z = a[2] + xv.z; o.w = a[3] + xv.w;
      *(float4*)(C + base + (size_t)f4 * 4) = o;
    }
  }
}

extern "C" void kernel_launch(void* const* d_in, const int* in_sizes, int n_in,
                              void* d_out, int out_size, void* d_ws, size_t ws_size,
                              hipStream_t stream) {
  (void)in_sizes; (void)n_in; (void)out_size; (void)ws_size;
  const float* x = (const float*)d_in[0];
  const float* gamma = (const float*)d_in[1];
  const float* beta = (const float*)d_in[2];
  const float* wqkv = (const float*)d_in[3];
  const float* wout = (const float*)d_in[4];
  float* outp = (float*)d_out;

  char* ws = (char*)d_ws;
  const size_t MB = 1024 * 1024;
  u16* wtT = (u16*)(ws + 0);                     // 128K
  u16* woutT = (u16*)(ws + (128 << 10));         // 128K
  float* partials = (float*)(ws + (512 << 10));  // 2M
  u8* Q8 = (u8*)(ws + 3 * MB);                   // 8M  fp8 Tt layout (Q rows flat)
  u8* Kt8 = (u8*)(ws + 12 * MB);                 // 8M  fp8 [z][1024][256]
  u8* Qt = (u8*)(ws + 21 * MB);                  // 8M  fp8 [z][256][1024]
  u8* Et = (u8*)(ws + 30 * MB);                  // 32M fp8 [z][p][i]

  combine_w<<<256, 256, 0, stream>>>(wqkv, wout, wtT, woutT);
  gnT<<<512, 512, 0, stream>>>(x, gamma, beta, wtT, Q8, Kt8);
  gemm_s8<<<dim3(32, 64), 256, 0, stream>>>(Q8, Kt8, Et, partials);
  qt8<<<dim3(16, 32), 256, 0, stream>>>(Q8, partials, Qt);
  gemm_of<<<dim3(32, 16), 512, 0, stream>>>(Et, Qt, woutT, x, outp);
}

// Round 11
// 85.815 us; speedup vs baseline: 1.1977x; 1.0502x over previous
//
#include <hip/hip_runtime.h>

typedef unsigned short u16;
typedef unsigned char u8;
typedef long long i64;
typedef __bf16 bf16x8 __attribute__((ext_vector_type(8)));
typedef float f32x4 __attribute__((ext_vector_type(4)));
typedef u16 u16x8 __attribute__((ext_vector_type(8)));

#define GLD16(g, l) __builtin_amdgcn_global_load_lds( \
    (const __attribute__((address_space(1))) void*)(g), \
    (__attribute__((address_space(3))) void*)(l), 16, 0, 0)
// counted vmcnt wait (N literal) -- lets prefetch loads stay in flight across barriers
#define VMW(N) asm volatile("s_waitcnt vmcnt(" #N ")" ::: "memory")
#define SCHB __builtin_amdgcn_sched_barrier(0)
#define SBAR __builtin_amdgcn_s_barrier()

__device__ __forceinline__ float bf2f(u16 u) {
  return __uint_as_float(((unsigned)u) << 16);
}
__device__ __forceinline__ u16 f2bf(float f) {  // RNE
  unsigned u = __float_as_uint(f);
  return (u16)((u + 0x7fffu + ((u >> 16) & 1u)) >> 16);
}
// ---- software fp8 e4m3fn fallback codec ----
__device__ __forceinline__ u8 f8e_sw(float v) {
  unsigned u = __float_as_uint(v);
  unsigned s = (u >> 24) & 0x80u;
  u &= 0x7fffffffu;
  if (u < 0x3c000000u) return (u8)s;
  int b = (int)((u + 0x7FFFFu + ((u >> 20) & 1u)) >> 20) - 960;
  b = b < 8 ? 8 : (b > 126 ? 126 : b);
  return (u8)(b | s);
}
// ---- hardware fp8 codec (gfx950) with sw fallback ----
__device__ __forceinline__ unsigned pk4(float a, float b, float c, float d) {
#if __has_builtin(__builtin_amdgcn_cvt_pk_fp8_f32)
  int r = __builtin_amdgcn_cvt_pk_fp8_f32(a, b, 0, false);
  r = __builtin_amdgcn_cvt_pk_fp8_f32(c, d, r, true);
  return (unsigned)r;
#else
  return (unsigned)f8e_sw(a) | ((unsigned)f8e_sw(b) << 8) |
         ((unsigned)f8e_sw(c) << 16) | ((unsigned)f8e_sw(d) << 24);
#endif
}
__device__ __forceinline__ u8 f8e1(float v) {
#if __has_builtin(__builtin_amdgcn_cvt_pk_fp8_f32)
  return (u8)(__builtin_amdgcn_cvt_pk_fp8_f32(v, v, 0, false) & 0xff);
#else
  return f8e_sw(v);
#endif
}
// 16B-slot swizzle key (bank-conflict-free fragment reads from GLD16-linear LDS)
__device__ __forceinline__ int sig(int r) { return (r ^ (r >> 3)) & 7; }

// ---- weight prep: wtT[d][c] = bf16(((Wq+Wk+Wv)/3)[c][d]);
//      wout8[d][c] = fp8(64 * w_out[c][d])  (x64 clears fp8 FTZ floor)
__global__ void combine_w(const float* __restrict__ wqkv, const float* __restrict__ wout,
                          u16* __restrict__ wtT, u8* __restrict__ wout8) {
  int c = blockIdx.x, d = threadIdx.x;
  float t = (wqkv[c * 768 + d] + wqkv[c * 768 + 256 + d] + wqkv[c * 768 + 512 + d]) * (1.0f / 3.0f);
  wtT[d * 256 + c] = f2bf(t);
  wout8[d * 256 + c] = f8e1(64.0f * wout[c * 256 + d]);
}

// ---- fused GroupNorm + GEMM-T, double-buffered. Tile 64x256, 8 waves.
__global__ __launch_bounds__(512) void gnT(
    const float* __restrict__ x, const float* __restrict__ gamma,
    const float* __restrict__ beta, const u16* __restrict__ wtT,
    u8* __restrict__ Q8, u8* __restrict__ Kt8) {
  __shared__ u16 lA[2][64 * 64];
  __shared__ u16 lB[2][256 * 64];
  const int m0 = blockIdx.x * 64;   // global pixel base (single batch per block)
  const int z = m0 >> 10;
  const int t = threadIdx.x, lane = t & 63;
  const int w = t >> 6, wr = w >> 2, wc = w & 3;
  f32x4 acc[2][4] = {};

#define GNT_STAGE(B, K0)                                                        \
  {                                                                             \
    _Pragma("unroll") for (int ch = 0; ch < 4; ch++) {                          \
      int flat = ch * 512 + t, row = flat >> 3, slot = flat & 7;                \
      GLD16(wtT + (size_t)row * 256 + (K0) + (slot ^ sig(row)) * 8,             \
            lB[B] + flat * 8);                                                  \
    }                                                                           \
    int row = t >> 3, grp = t & 7;                                              \
    const float* xp = x + (size_t)(m0 + row) * 256 + (K0) + grp * 8;            \
    float4 a = *(const float4*)xp, b = *(const float4*)(xp + 4);                \
    float mu = (a.x + a.y + a.z + a.w + b.x + b.y + b.z + b.w) * 0.125f;        \
    float d0 = a.x - mu, d1 = a.y - mu, d2 = a.z - mu, d3 = a.w - mu;           \
    float d4 = b.x - mu, d5 = b.y - mu, d6 = b.z - mu, d7 = b.w - mu;           \
    float var = (d0 * d0 + d1 * d1 + d2 * d2 + d3 * d3 +                        \
                 d4 * d4 + d5 * d5 + d6 * d6 + d7 * d7) * 0.125f;               \
    float rs = rsqrtf(var + 1e-6f);                                             \
    const float4 g0 = *(const float4*)(gamma + (K0) + grp * 8);                 \
    const float4 g1 = *(const float4*)(gamma + (K0) + grp * 8 + 4);             \
    const float4 e0 = *(const float4*)(beta + (K0) + grp * 8);                  \
    const float4 e1 = *(const float4*)(beta + (K0) + grp * 8 + 4);              \
    u16x8 o;                                                                    \
    o[0] = f2bf(g0.x * (d0 * rs) + e0.x); o[1] = f2bf(g0.y * (d1 * rs) + e0.y); \
    o[2] = f2bf(g0.z * (d2 * rs) + e0.z); o[3] = f2bf(g0.w * (d3 * rs) + e0.w); \
    o[4] = f2bf(g1.x * (d4 * rs) + e1.x); o[5] = f2bf(g1.y * (d5 * rs) + e1.y); \
    o[6] = f2bf(g1.z * (d6 * rs) + e1.z); o[7] = f2bf(g1.w * (d7 * rs) + e1.w); \
    *(u16x8*)(lA[B] + row * 64 + (grp ^ sig(row)) * 8) = o;                     \
  }

  GNT_STAGE(0, 0);
  __syncthreads();
  for (int it = 0; it < 4; it++) {
    if (it < 3) { GNT_STAGE((it + 1) & 1, (it + 1) * 64); }
    const u16* la = lA[it & 1];
    const u16* lb = lB[it & 1];
#pragma unroll
    for (int kk = 0; kk < 2; kk++) {
      bf16x8 af[2], bfr[4];
#pragma unroll
      for (int mi = 0; mi < 2; mi++) {
        int m = wr * 32 + mi * 16 + (lane & 15);
        af[mi] = *(const bf16x8*)(la + m * 64 + ((kk * 32 + (lane >> 4) * 8) ^ (sig(m) << 3)));
      }
#pragma unroll
      for (int ni = 0; ni < 4; ni++) {
        int n = wc * 64 + ni * 16 + (lane & 15);
        bfr[ni] = *(const bf16x8*)(lb + n * 64 + ((kk * 32 + (lane >> 4) * 8) ^ (sig(n) << 3)));
      }
#pragma unroll
      for (int mi = 0; mi < 2; mi++)
#pragma unroll
        for (int ni = 0; ni < 4; ni++)
          acc[mi][ni] = __builtin_amdgcn_mfma_f32_16x16x32_bf16(af[mi], bfr[ni], acc[mi][ni], 0, 0, 0);
    }
    __syncthreads();
  }

  const int rb = m0 + wr * 32 + ((lane >> 4) << 2);  // global pixel, %4 == 0
  const int cb = wc * 64 + (lane & 15);
  u8* kt = (u8*)lB[0];          // 16KB: Kt8 repack [1024 rows][16B]
  u8* qtile = (u8*)lB[1];       // 20KB: Q8 repack [256 c][80B stride, 64B data]
#pragma unroll
  for (int mi = 0; mi < 2; mi++)
#pragma unroll
    for (int ni = 0; ni < 4; ni++) {
      int P0 = rb + mi * 16, c = cb + ni * 16;
      int pl = P0 - m0;                     // 0..63, %4==0
      unsigned pk = pk4(acc[mi][ni][0], acc[mi][ni][1], acc[mi][ni][2], acc[mi][ni][3]);
#pragma unroll
      for (int j = 0; j < 4; j++)
        kt[(j * 256 + c) * 16 + (pl >> 2)] = (u8)(pk >> (8 * j));
      *(unsigned*)(qtile + c * 80 + pl) = pk;
    }
  __syncthreads();
  const int ckb = (m0 & 1023) >> 2;
  u8* Kz = Kt8 + (size_t)z * 262144;
  u8* Qz = Q8 + (size_t)z * 262144;
#pragma unroll
  for (int r2 = 0; r2 < 2; r2++) {
    int r = t * 2 + r2;
    uint4 v = *(const uint4*)(kt + r * 16);
    *(uint4*)(Kz + (size_t)r * 256 + ckb) = v;
  }
#pragma unroll
  for (int ph = 0; ph < 2; ph++) {
    int idx = ph * 512 + t, c = idx >> 2, q = idx & 3;
    uint4 v = *(const uint4*)(qtile + c * 80 + q * 16);
    *(uint4*)(Qz + (size_t)c * 1024 + (m0 & 1023) + q * 16) = v;
  }
#undef GNT_STAGE
}

// ---- GEMM-S (fp8): Et[p,i] = fp8(exp((Q@K)[i,p]/16)) + row partial sums.
// 2-stage BK=128 dbuf, counted vmcnt.
__global__ __launch_bounds__(256) void gemm_s8(
    const u8* __restrict__ Q8, const u8* __restrict__ Kt8,
    u8* __restrict__ Et, float* __restrict__ partials) {
  __shared__ u8 lA[2][128 * 128];
  __shared__ u8 lB[2][128 * 128];
  const int z = blockIdx.x;
  const int mb = blockIdx.y & 7, pb = blockIdx.y >> 3;
  const u8* Az = Q8 + (size_t)z * 262144;
  const u8* Bz = Kt8 + (size_t)z * 262144;
  u8* Ez = Et + (size_t)z * 1048576;
  const int m0 = mb * 128, n0 = pb * 128;
  const int t = threadIdx.x, lane = t & 63;
  const int wr = (t >> 6) >> 1, wc = (t >> 6) & 1;
  f32x4 acc[4][4] = {};

#define S8_STAGE(B, K0)                                                       \
  {                                                                           \
    _Pragma("unroll") for (int ch = 0; ch < 4; ch++) {                        \
      int flat = ch * 256 + t, row = flat >> 3, slot = flat & 7;              \
      GLD16(Az + (size_t)(m0 + row) * 256 + (K0) + (slot ^ sig(row)) * 16,    \
            lA[B] + flat * 16);                                               \
    }                                                                         \
    _Pragma("unroll") for (int ch = 0; ch < 4; ch++) {                        \
      int flat = ch * 256 + t, row = flat >> 3, slot = flat & 7;              \
      GLD16(Bz + (size_t)(n0 + row) * 256 + (K0) + (slot ^ sig(row)) * 16,    \
            lB[B] + flat * 16);                                               \
    }                                                                         \
  }
#define S8_COMP(LA, LB)                                                       \
  _Pragma("unroll") for (int kk = 0; kk < 4; kk++) {                          \
    i64 af[4], bfv[4];                                                        \
    int koff = kk * 32 + (lane >> 4) * 8;                                     \
    _Pragma("unroll") for (int mi = 0; mi < 4; mi++) {                        \
      int m = wr * 64 + mi * 16 + (lane & 15);                                \
      af[mi] = *(const i64*)((LA) + m * 128 + (koff ^ (sig(m) << 4)));        \
    }                                                                         \
    _Pragma("unroll") for (int ni = 0; ni < 4; ni++) {                        \
      int n = wc * 64 + ni * 16 + (lane & 15);                                \
      bfv[ni] = *(const i64*)((LB) + n * 128 + (koff ^ (sig(n) << 4)));       \
    }                                                                         \
    _Pragma("unroll") for (int mi = 0; mi < 4; mi++)                          \
      _Pragma("unroll") for (int ni = 0; ni < 4; ni++)                        \
        acc[mi][ni] = __builtin_amdgcn_mfma_f32_16x16x32_fp8_fp8(             \
            af[mi], bfv[ni], acc[mi][ni], 0, 0, 0);                           \
  }

  S8_STAGE(0, 0);
  S8_STAGE(1, 128);
  VMW(8); SCHB; SBAR; SCHB;
  __builtin_amdgcn_s_setprio(1);
  S8_COMP(lA[0], lB[0]);
  __builtin_amdgcn_s_setprio(0);
  VMW(0); SCHB; SBAR; SCHB;
  __builtin_amdgcn_s_setprio(1);
  S8_COMP(lA[1], lB[1]);
  __builtin_amdgcn_s_setprio(0);
  __syncthreads();
#undef S8_STAGE
#undef S8_COMP

  u8* ldsC = lA[0];  // 128p x 128i fp8 tile (16KB)
  const int rbl = wr * 64 + ((lane >> 4) << 2);  // local i
  const int cbl = wc * 64 + (lane & 15);         // local p
  const float SCL = 0.0625f * 1.44269504089f;    // exp(x) = exp2(x*log2e)
  float ps[4][4] = {};
#pragma unroll
  for (int mi = 0; mi < 4; mi++)
#pragma unroll
    for (int ni = 0; ni < 4; ni++) {
      int pl = cbl + ni * 16, ib = rbl + mi * 16;
      float e0 = exp2f(acc[mi][ni][0] * SCL);
      float e1 = exp2f(acc[mi][ni][1] * SCL);
      float e2 = exp2f(acc[mi][ni][2] * SCL);
      float e3 = exp2f(acc[mi][ni][3] * SCL);
      ps[mi][0] += e0; ps[mi][1] += e1; ps[mi][2] += e2; ps[mi][3] += e3;
      *(unsigned*)(ldsC + pl * 128 + (ib ^ ((pl & 7) << 4))) = pk4(e0, e1, e2, e3);
    }
#pragma unroll
  for (int mi = 0; mi < 4; mi++)
#pragma unroll
    for (int j = 0; j < 4; j++) {
      float v = ps[mi][j];
      v += __shfl_xor(v, 1); v += __shfl_xor(v, 2);
      v += __shfl_xor(v, 4); v += __shfl_xor(v, 8);
      if ((lane & 15) == 0)
        partials[(size_t)(z * 1024 + m0 + rbl + mi * 16 + j) * 16 + pb * 2 + wc] = v;
    }
  __syncthreads();
#pragma unroll
  for (int ph = 0; ph < 4; ph++) {
    int pl = ph * 32 + (t >> 3), ich = (t & 7) * 16;
    uint4 v = *(const uint4*)(ldsC + pl * 128 + (ich ^ ((pl & 7) << 4)));
    *(uint4*)(Ez + (size_t)(n0 + pl) * 1024 + m0 + ich) = v;
  }
}

// ---- GEMM-G (fp8): Gt[d][i] = fp8( (128/L[i]) * sum_c wout8[d,c]*Q8[i,c] )
// (= fp8(8192 * rinv[i] * G[i,d]) since wout8 = 64*wout). Single-stage K=256,
// tile 256d x 128i, 8 waves (2x4). rinv reduction fused; LDS-repacked store.
__global__ __launch_bounds__(512) void gemm_g(
    const u8* __restrict__ wout8, const u8* __restrict__ Q8,
    const float* __restrict__ partials, u8* __restrict__ Gt) {
  __shared__ u8 lA[256 * 256];   // 64KB wout8 (whole A)
  __shared__ u8 lB[128 * 256];   // 32KB Q8 slice; reused as repack tile
  __shared__ float rv[128];
  const int z = blockIdx.x;      // grid (32, 8): id%8 == z%8 -> XCD locality
  const int i0 = blockIdx.y * 128;
  const u8* Bz = Q8 + (size_t)z * 262144;
  u8* Gz = Gt + (size_t)z * 262144;
  const int t = threadIdx.x, lane = t & 63;
  const int w = t >> 6, wr = w >> 2, wc = w & 3;  // wr: d-half, wc: i-quarter
#pragma unroll
  for (int ch = 0; ch < 8; ch++) {
    int flat = ch * 512 + t, row = flat >> 4, slot = flat & 15;
    GLD16(wout8 + (size_t)row * 256 + (slot ^ sig(row)) * 16, lA + flat * 16);
  }
#pragma unroll
  for (int ch = 0; ch < 4; ch++) {
    int flat = ch * 512 + t, row = flat >> 4, slot = flat & 15;
    GLD16(Bz + (size_t)(i0 + row) * 256 + (slot ^ sig(row)) * 16, lB + flat * 16);
  }
  if (t < 128) {  // rinv for this i-range (partials complete after gemm_s8)
    const float4* p = (const float4*)(partials + (size_t)(z * 1024 + i0 + t) * 16);
    float4 a = p[0], b = p[1], c = p[2], d = p[3];
    float s = ((a.x + a.y) + (a.z + a.w)) + ((b.x + b.y) + (b.z + b.w)) +
              ((c.x + c.y) + (c.z + c.w)) + ((d.x + d.y) + (d.z + d.w));
    rv[t] = 128.0f / s;
  }
  __syncthreads();
  f32x4 acc[8][2] = {};
#pragma unroll
  for (int kk = 0; kk < 8; kk++) {
    i64 af[8], bfv[2];
    int koff = kk * 32 + (lane >> 4) * 8;
#pragma unroll
    for (int mi = 0; mi < 8; mi++) {
      int m = wr * 128 + mi * 16 + (lane & 15);
      af[mi] = *(const i64*)(lA + m * 256 + (koff ^ (sig(m) << 4)));
    }
#pragma unroll
    for (int ni = 0; ni < 2; ni++) {
      int n = wc * 32 + ni * 16 + (lane & 15);
      bfv[ni] = *(const i64*)(lB + n * 256 + (koff ^ (sig(n) << 4)));
    }
#pragma unroll
    for (int mi = 0; mi < 8; mi++)
#pragma unroll
      for (int ni = 0; ni < 2; ni++)
        acc[mi][ni] = __builtin_amdgcn_mfma_f32_16x16x32_fp8_fp8(af[mi], bfv[ni], acc[mi][ni], 0, 0, 0);
  }
  __syncthreads();               // all lB fragment reads done
  u8* ldsG = lB;                 // repack [256 d][128 i], XOR-staggered
#pragma unroll
  for (int mi = 0; mi < 8; mi++)
#pragma unroll
    for (int ni = 0; ni < 2; ni++) {
      int i = wc * 32 + ni * 16 + (lane & 15);
      float r = rv[i];
#pragma unroll
      for (int j = 0; j < 4; j++) {
        int d = wr * 128 + mi * 16 + ((lane >> 4) << 2) + j;
        ldsG[d * 128 + (i ^ ((d & 7) << 4))] = f8e1(acc[mi][ni][j] * r);
      }
    }
  __syncthreads();
#pragma unroll
  for (int ch = 0; ch < 4; ch++) {
    int flat = ch * 512 + t, d = flat >> 3, q = flat & 7;
    uint4 v = *(const uint4*)(ldsG + d * 128 + ((q * 16) ^ ((d & 7) << 4)));
    *(uint4*)(Gz + (size_t)d * 1024 + i0 + q * 16) = v;
  }
}

// ---- GEMM-FIN (fp8): final[p,d] = (1/8192)*sum_i Et[p,i]*Gt[d,i] + x[p,d].
// 64p x 256d tile, 80KB LDS -> 2 blocks/CU, counted vmcnt(5), single phase.
// Epilogue: f32 spill -> coalesced x-add-store.
__global__ __launch_bounds__(512, 4) void gemm_fin(
    const u8* __restrict__ Et, const u8* __restrict__ Gt,
    const float* __restrict__ x, float* __restrict__ C) {
  __shared__ char smem[81920];
  const int z = blockIdx.x;      // grid (32, 16): id%8 == z%8 -> Gt panel per XCD
  const int m0 = blockIdx.y * 64;
  const u8* Az = Et + (size_t)z * 1048576;
  const u8* Bz = Gt + (size_t)z * 262144;
  const int t = threadIdx.x, lane = t & 63;
  const int w = t >> 6, wr = w >> 2, wc = w & 3;
  f32x4 acc[2][4] = {};

#define FIN_STAGE(B, K0)                                                      \
  {                                                                           \
    u8* la_ = (u8*)smem + (B) * 8192;                                         \
    u8* lb_ = (u8*)smem + 16384 + (B) * 32768;                                \
    {                                                                         \
      int row = t >> 3, slot = t & 7;                                         \
      GLD16(Az + (size_t)(m0 + row) * 1024 + (K0) + (slot ^ sig(row)) * 16,   \
            la_ + t * 16);                                                    \
    }                                                                         \
    _Pragma("unroll") for (int ch = 0; ch < 4; ch++) {                        \
      int flat = ch * 512 + t, row = flat >> 3, slot = flat & 7;              \
      GLD16(Bz + (size_t)row * 1024 + (K0) + (slot ^ sig(row)) * 16,          \
            lb_ + flat * 16);                                                 \
    }                                                                         \
  }

  FIN_STAGE(0, 0);
  for (int it = 0; it < 8; it++) {
    if (it < 7) {
      FIN_STAGE((it + 1) & 1, (it + 1) * 128);
      VMW(5);
    } else {
      VMW(0);
    }
    SCHB; SBAR; SCHB;
    const u8* la = (const u8*)smem + (it & 1) * 8192;
    const u8* lb = (const u8*)smem + 16384 + (it & 1) * 32768;
    __builtin_amdgcn_s_setprio(1);
#pragma unroll
    for (int kk = 0; kk < 4; kk++) {
      i64 af[2], bfv[4];
      int koff = kk * 32 + (lane >> 4) * 8;
#pragma unroll
      for (int mi = 0; mi < 2; mi++) {
        int m = wr * 32 + mi * 16 + (lane & 15);
        af[mi] = *(const i64*)(la + m * 128 + (koff ^ (sig(m) << 4)));
      }
#pragma unroll
      for (int ni = 0; ni < 4; ni++) {
        int n = wc * 64 + ni * 16 + (lane & 15);
        bfv[ni] = *(const i64*)(lb + n * 128 + (koff ^ (sig(n) << 4)));
      }
#pragma unroll
      for (int mi = 0; mi < 2; mi++)
#pragma unroll
        for (int ni = 0; ni < 4; ni++)
          acc[mi][ni] = __builtin_amdgcn_mfma_f32_16x16x32_fp8_fp8(af[mi], bfv[ni], acc[mi][ni], 0, 0, 0);
    }
    __builtin_amdgcn_s_setprio(0);
    SBAR;
  }
#undef FIN_STAGE

  // epilogue: scale, spill f32 to [0,64K), coalesced x-add-store
  {
#pragma unroll
    for (int mi = 0; mi < 2; mi++)
#pragma unroll
      for (int ni = 0; ni < 4; ni++)
#pragma unroll
        for (int j = 0; j < 4; j++) {
          int pl = wr * 32 + mi * 16 + ((lane >> 4) << 2) + j;
          int c = wc * 64 + ni * 16 + (lane & 15);
          *(float*)(smem + ((pl * 1024 + c * 4) ^ ((pl & 7) << 4))) =
              acc[mi][ni][j] * (1.0f / 8192.0f);
        }
    __syncthreads();
    const size_t base = ((size_t)z * 1024 + m0) * 256;
#pragma unroll
    for (int pi = 0; pi < 8; pi++) {
      int f4 = pi * 512 + t;
      int row = f4 >> 6, ch = f4 & 63;
      f32x4 a = *(const f32x4*)(smem + row * 1024 + ((ch * 16) ^ ((row & 7) << 4)));
      const float4 xv = *(const float4*)(x + base + (size_t)f4 * 4);
      float4 o;
      o.x = a[0] + xv.x; o.y = a[1] + xv.y; o.z = a[2] + xv.z; o.w = a[3] + xv.w;
      *(float4*)(C + base + (size_t)f4 * 4) = o;
    }
  }
}

extern "C" void kernel_launch(void* const* d_in, const int* in_sizes, int n_in,
                              void* d_out, int out_size, void* d_ws, size_t ws_size,
                              hipStream_t stream) {
  (void)in_sizes; (void)n_in; (void)out_size; (void)ws_size;
  const float* x = (const float*)d_in[0];
  const float* gamma = (const float*)d_in[1];
  const float* beta = (const float*)d_in[2];
  const float* wqkv = (const float*)d_in[3];
  const float* wout = (const float*)d_in[4];
  float* outp = (float*)d_out;

  char* ws = (char*)d_ws;
  const size_t MB = 1024 * 1024;
  u16* wtT = (u16*)(ws + 0);                     // 128K bf16
  u8* wout8 = (u8*)(ws + (128 << 10));           // 64K  fp8 (64*w_out^T)
  float* partials = (float*)(ws + (512 << 10));  // 2M
  u8* Q8 = (u8*)(ws + 3 * MB);                   // 8M  fp8 Tt layout (Q rows flat)
  u8* Kt8 = (u8*)(ws + 12 * MB);                 // 8M  fp8 [z][1024][256]
  u8* Gt = (u8*)(ws + 21 * MB);                  // 8M  fp8 [z][256 d][1024 i]
  u8* Et = (u8*)(ws + 30 * MB);                  // 32M fp8 [z][p][i]

  combine_w<<<256, 256, 0, stream>>>(wqkv, wout, wtT, wout8);
  gnT<<<512, 512, 0, stream>>>(x, gamma, beta, wtT, Q8, Kt8);
  gemm_s8<<<dim3(32, 64), 256, 0, stream>>>(Q8, Kt8, Et, partials);
  gemm_g<<<dim3(32, 8), 512, 0, stream>>>(wout8, Q8, partials, Gt);
  gemm_fin<<<dim3(32, 16), 512, 0, stream>>>(Et, Gt, x, outp);
}